// Round 1
// baseline (1142.459 us; speedup 1.0000x reference)
//
#include <hip/hip_runtime.h>
#include <math.h>

#define B_ 2
#define S_ 2048
#define D_ 1024
#define H_ 16
#define DK_ 64
#define M_ (B_*S_)   // 4096

// ---------------- fp32 GEMM: C = X @ W^T + bias ----------------
// X: [M][K=1024] row-major, W: [N=1024][K=1024] row-major (torch Linear weight)
// OUT_MODE 0: out[M][N] row-major; OUT_MODE 1: out scattered to [B][H][S][DK]
template<int OUT_MODE>
__global__ __launch_bounds__(256)
void sgemm_xwT(const float* __restrict__ X, const float* __restrict__ W,
               const float* __restrict__ bias, float* __restrict__ out)
{
    constexpr int K = D_;
    constexpr int N = D_;
    __shared__ float As[16][132];   // [k][m] transposed, pad to 132
    __shared__ float Bs[16][132];   // [k][n] transposed
    const int tid = threadIdx.x;
    const int tx = tid & 15, ty = tid >> 4;
    const int rowBase = blockIdx.y * 128;
    const int colBase = blockIdx.x * 128;

    float acc[8][8];
    #pragma unroll
    for (int i = 0; i < 8; ++i)
        #pragma unroll
        for (int j = 0; j < 8; ++j) acc[i][j] = 0.f;

    for (int k0 = 0; k0 < K; k0 += 16) {
        __syncthreads();
        // stage A-tile (128 rows x 16 k) and B-tile, transposed into LDS
        #pragma unroll
        for (int it = 0; it < 2; ++it) {
            int f = it * 256 + tid;          // 512 float4 per tile
            int r = f >> 2, kp = (f & 3) * 4;
            float4 a = *(const float4*)&X[(size_t)(rowBase + r) * K + k0 + kp];
            As[kp + 0][r] = a.x; As[kp + 1][r] = a.y;
            As[kp + 2][r] = a.z; As[kp + 3][r] = a.w;
            float4 b = *(const float4*)&W[(size_t)(colBase + r) * K + k0 + kp];
            Bs[kp + 0][r] = b.x; Bs[kp + 1][r] = b.y;
            Bs[kp + 2][r] = b.z; Bs[kp + 3][r] = b.w;
        }
        __syncthreads();
        #pragma unroll
        for (int kk = 0; kk < 16; ++kk) {
            float a[8], b[8];
            *(float4*)&a[0] = *(const float4*)&As[kk][ty * 4];
            *(float4*)&a[4] = *(const float4*)&As[kk][ty * 4 + 64];
            *(float4*)&b[0] = *(const float4*)&Bs[kk][tx * 4];
            *(float4*)&b[4] = *(const float4*)&Bs[kk][tx * 4 + 64];
            #pragma unroll
            for (int i = 0; i < 8; ++i)
                #pragma unroll
                for (int j = 0; j < 8; ++j)
                    acc[i][j] = fmaf(a[i], b[j], acc[i][j]);
        }
    }
    // epilogue: + bias, scatter
    #pragma unroll
    for (int i = 0; i < 8; ++i) {
        int m = rowBase + ((i < 4) ? (ty * 4 + i) : (64 + ty * 4 + i - 4));
        #pragma unroll
        for (int jb = 0; jb < 2; ++jb) {
            int j0 = colBase + (jb ? (64 + tx * 4) : (tx * 4));
            float4 bv = *(const float4*)&bias[j0];
            float4 v;
            v.x = acc[i][jb * 4 + 0] + bv.x;
            v.y = acc[i][jb * 4 + 1] + bv.y;
            v.z = acc[i][jb * 4 + 2] + bv.z;
            v.w = acc[i][jb * 4 + 3] + bv.w;
            if (OUT_MODE == 0) {
                *(float4*)&out[(size_t)m * N + j0] = v;
            } else {
                int bb = m >> 11, s = m & 2047;      // m = b*S + s
                int h = j0 >> 6, d = j0 & 63;        // j = h*64 + d
                *(float4*)&out[(((size_t)bb * H_ + h) * S_ + s) * DK_ + d] = v;
            }
        }
    }
}

// ---------------- fp32 flash attention with the non-standard scoring ----------
// scores = mask ? exp(q.k)/8 : -1e9 ; softmax over k ; O = P V
// Q/K/V: [B][H][S][64] fp32. Octx: [B][S][H*64] fp32.
__global__ __launch_bounds__(256)
void flash_fp32(const float* __restrict__ Qh, const float* __restrict__ Kh,
                const float* __restrict__ Vh, const int* __restrict__ mask,
                float* __restrict__ Octx)
{
    __shared__ float Qs[64 * 71];    // [r][d] stride 71
    __shared__ float KsPT[64 * 71];  // K-tile [c][d] stride 71; reused as P^T [k][r] stride 69
    __shared__ float Vs[64 * 68];    // [k][d] stride 68 (float4-aligned)
    const int tid = threadIdx.x;
    const int tx = tid & 15, ty = tid >> 4;
    const int q0 = blockIdx.x * 64;
    const int h = blockIdx.y, b = blockIdx.z;
    const float* Qbase = Qh + (((size_t)b * H_ + h) * S_ + q0) * DK_;
    const float* Kbase = Kh + (((size_t)b * H_ + h) * S_) * DK_;
    const float* Vbase = Vh + (((size_t)b * H_ + h) * S_) * DK_;
    const int*   mbase = mask + ((size_t)b * S_ + q0) * S_;

    // stage Q once
    #pragma unroll
    for (int it = 0; it < 4; ++it) {
        int f = it * 256 + tid;
        int r = f >> 4, d0 = (f & 15) * 4;
        float4 q = *(const float4*)&Qbase[r * DK_ + d0];
        Qs[r * 71 + d0 + 0] = q.x; Qs[r * 71 + d0 + 1] = q.y;
        Qs[r * 71 + d0 + 2] = q.z; Qs[r * 71 + d0 + 3] = q.w;
    }

    float m_run[4], l_run[4], acc[4][4];
    #pragma unroll
    for (int i = 0; i < 4; ++i) {
        m_run[i] = -INFINITY; l_run[i] = 0.f;
        #pragma unroll
        for (int j = 0; j < 4; ++j) acc[i][j] = 0.f;
    }

    for (int s0 = 0; s0 < S_; s0 += 64) {
        __syncthreads();   // previous PV done before overwriting K/V/PT
        // stage K and V tiles
        #pragma unroll
        for (int it = 0; it < 4; ++it) {
            int f = it * 256 + tid;
            int r = f >> 4, d0 = (f & 15) * 4;
            float4 kv = *(const float4*)&Kbase[(size_t)(s0 + r) * DK_ + d0];
            KsPT[r * 71 + d0 + 0] = kv.x; KsPT[r * 71 + d0 + 1] = kv.y;
            KsPT[r * 71 + d0 + 2] = kv.z; KsPT[r * 71 + d0 + 3] = kv.w;
            float4 vv = *(const float4*)&Vbase[(size_t)(s0 + r) * DK_ + d0];
            *(float4*)&Vs[r * 68 + d0] = vv;
        }
        __syncthreads();

        // S-tile: sf[i][j] = q_{r0+i} . k_{c0+j}   (fp32)
        float sf[4][4];
        #pragma unroll
        for (int i = 0; i < 4; ++i)
            #pragma unroll
            for (int j = 0; j < 4; ++j) sf[i][j] = 0.f;
        #pragma unroll 4
        for (int d = 0; d < 64; ++d) {
            float qa[4], kb[4];
            #pragma unroll
            for (int i = 0; i < 4; ++i) qa[i] = Qs[(ty * 4 + i) * 71 + d];
            #pragma unroll
            for (int j = 0; j < 4; ++j) kb[j] = KsPT[(tx * 4 + j) * 71 + d];
            #pragma unroll
            for (int i = 0; i < 4; ++i)
                #pragma unroll
                for (int j = 0; j < 4; ++j)
                    sf[i][j] = fmaf(qa[i], kb[j], sf[i][j]);
        }

        // t = mask ? exp(s)/8 : -1e9 ; online softmax update
        float p[4][4], tm[4];
        #pragma unroll
        for (int i = 0; i < 4; ++i) {
            const int4 mv = *(const int4*)&mbase[(size_t)(ty * 4 + i) * S_ + s0 + tx * 4];
            p[i][0] = (mv.x == 0) ? -1e9f : expf(sf[i][0]) * 0.125f;
            p[i][1] = (mv.y == 0) ? -1e9f : expf(sf[i][1]) * 0.125f;
            p[i][2] = (mv.z == 0) ? -1e9f : expf(sf[i][2]) * 0.125f;
            p[i][3] = (mv.w == 0) ? -1e9f : expf(sf[i][3]) * 0.125f;
            tm[i] = fmaxf(fmaxf(p[i][0], p[i][1]), fmaxf(p[i][2], p[i][3]));
        }
        #pragma unroll
        for (int off = 1; off < 16; off <<= 1) {
            #pragma unroll
            for (int i = 0; i < 4; ++i)
                tm[i] = fmaxf(tm[i], __shfl_xor(tm[i], off, 64));
        }
        float rs[4];
        #pragma unroll
        for (int i = 0; i < 4; ++i) {
            float m_new = fmaxf(m_run[i], tm[i]);
            float scale = expf(m_run[i] - m_new);   // -inf - finite -> 0, exact
            float sum = 0.f;
            #pragma unroll
            for (int j = 0; j < 4; ++j) { p[i][j] = expf(p[i][j] - m_new); sum += p[i][j]; }
            rs[i] = sum;
            l_run[i] *= scale;
            #pragma unroll
            for (int j = 0; j < 4; ++j) acc[i][j] *= scale;
            m_run[i] = m_new;
        }
        #pragma unroll
        for (int off = 1; off < 16; off <<= 1) {
            #pragma unroll
            for (int i = 0; i < 4; ++i)
                rs[i] += __shfl_xor(rs[i], off, 64);
        }
        #pragma unroll
        for (int i = 0; i < 4; ++i) l_run[i] += rs[i];

        __syncthreads();   // all K reads done -> reuse buffer as P^T
        #pragma unroll
        for (int j = 0; j < 4; ++j)
            #pragma unroll
            for (int i = 0; i < 4; ++i)
                KsPT[(tx * 4 + j) * 69 + ty * 4 + i] = p[i][j];
        __syncthreads();

        // PV: acc[i][j] += sum_k P^T[k][r0+i] * V[k][c0+j]
        #pragma unroll 4
        for (int kk = 0; kk < 64; ++kk) {
            float pv[4];
            #pragma unroll
            for (int i = 0; i < 4; ++i) pv[i] = KsPT[kk * 69 + ty * 4 + i];
            float4 vv = *(const float4*)&Vs[kk * 68 + tx * 4];
            #pragma unroll
            for (int i = 0; i < 4; ++i) {
                acc[i][0] = fmaf(pv[i], vv.x, acc[i][0]);
                acc[i][1] = fmaf(pv[i], vv.y, acc[i][1]);
                acc[i][2] = fmaf(pv[i], vv.z, acc[i][2]);
                acc[i][3] = fmaf(pv[i], vv.w, acc[i][3]);
            }
        }
    }

    // write O (merge heads): Octx[b][s][h*64+d]
    #pragma unroll
    for (int i = 0; i < 4; ++i) {
        float inv = 1.0f / l_run[i];
        int srow = q0 + ty * 4 + i;
        float4 o;
        o.x = acc[i][0] * inv; o.y = acc[i][1] * inv;
        o.z = acc[i][2] * inv; o.w = acc[i][3] * inv;
        *(float4*)&Octx[((size_t)b * S_ + srow) * D_ + h * DK_ + tx * 4] = o;
    }
}

extern "C" void kernel_launch(void* const* d_in, const int* in_sizes, int n_in,
                              void* d_out, int out_size, void* d_ws, size_t ws_size,
                              hipStream_t stream)
{
    const float* query = (const float*)d_in[0];
    const float* key_  = (const float*)d_in[1];
    const float* value = (const float*)d_in[2];
    const int*   mask  = (const int*)d_in[3];
    const float* Wq = (const float*)d_in[4];
    const float* bq = (const float*)d_in[5];
    const float* Wk = (const float*)d_in[6];
    const float* bk = (const float*)d_in[7];
    const float* Wv = (const float*)d_in[8];
    const float* bv = (const float*)d_in[9];
    const float* Wo = (const float*)d_in[10];
    const float* bo = (const float*)d_in[11];

    float* ws = (float*)d_ws;
    const size_t hsz = (size_t)B_ * H_ * S_ * DK_;   // 4,194,304 floats
    float* Qh   = ws;
    float* Kh   = Qh + hsz;
    float* Vh   = Kh + hsz;
    float* Octx = Vh + hsz;
    float* out  = (float*)d_out;

    dim3 gg(D_ / 128, M_ / 128);   // 8 x 32
    sgemm_xwT<1><<<gg, 256, 0, stream>>>(query, Wq, bq, Qh);
    sgemm_xwT<1><<<gg, 256, 0, stream>>>(key_,  Wk, bk, Kh);
    sgemm_xwT<1><<<gg, 256, 0, stream>>>(value, Wv, bv, Vh);

    dim3 fg(S_ / 64, H_, B_);      // 32 x 16 x 2
    flash_fp32<<<fg, 256, 0, stream>>>(Qh, Kh, Vh, mask, Octx);

    sgemm_xwT<0><<<gg, 256, 0, stream>>>(Octx, Wo, bo, out);
}

// Round 2
// 700.166 us; speedup vs baseline: 1.6317x; 1.6317x over previous
//
#include <hip/hip_runtime.h>
#include <math.h>

#define B_ 2
#define S_ 2048
#define D_ 1024
#define H_ 16
#define DK_ 64
#define M_ (B_*S_)   // 4096

typedef __attribute__((ext_vector_type(8))) _Float16 f16x8;
typedef __attribute__((ext_vector_type(4))) _Float16 f16x4;
typedef __attribute__((ext_vector_type(4))) float f32x4;

#define MFMA16(a, b, c) __builtin_amdgcn_mfma_f32_16x16x32_f16((a), (b), (c), 0, 0, 0)

// ---------------- fp32 GEMM: C = X @ W^T + bias (unchanged, passing) ----------
template<int OUT_MODE>
__global__ __launch_bounds__(256)
void sgemm_xwT(const float* __restrict__ X, const float* __restrict__ W,
               const float* __restrict__ bias, float* __restrict__ out)
{
    constexpr int K = D_;
    constexpr int N = D_;
    __shared__ float As[16][132];
    __shared__ float Bs[16][132];
    const int tid = threadIdx.x;
    const int tx = tid & 15, ty = tid >> 4;
    const int rowBase = blockIdx.y * 128;
    const int colBase = blockIdx.x * 128;

    float acc[8][8];
    #pragma unroll
    for (int i = 0; i < 8; ++i)
        #pragma unroll
        for (int j = 0; j < 8; ++j) acc[i][j] = 0.f;

    for (int k0 = 0; k0 < K; k0 += 16) {
        __syncthreads();
        #pragma unroll
        for (int it = 0; it < 2; ++it) {
            int f = it * 256 + tid;
            int r = f >> 2, kp = (f & 3) * 4;
            float4 a = *(const float4*)&X[(size_t)(rowBase + r) * K + k0 + kp];
            As[kp + 0][r] = a.x; As[kp + 1][r] = a.y;
            As[kp + 2][r] = a.z; As[kp + 3][r] = a.w;
            float4 b = *(const float4*)&W[(size_t)(colBase + r) * K + k0 + kp];
            Bs[kp + 0][r] = b.x; Bs[kp + 1][r] = b.y;
            Bs[kp + 2][r] = b.z; Bs[kp + 3][r] = b.w;
        }
        __syncthreads();
        #pragma unroll
        for (int kk = 0; kk < 16; ++kk) {
            float a[8], b[8];
            *(float4*)&a[0] = *(const float4*)&As[kk][ty * 4];
            *(float4*)&a[4] = *(const float4*)&As[kk][ty * 4 + 64];
            *(float4*)&b[0] = *(const float4*)&Bs[kk][tx * 4];
            *(float4*)&b[4] = *(const float4*)&Bs[kk][tx * 4 + 64];
            #pragma unroll
            for (int i = 0; i < 8; ++i)
                #pragma unroll
                for (int j = 0; j < 8; ++j)
                    acc[i][j] = fmaf(a[i], b[j], acc[i][j]);
        }
    }
    #pragma unroll
    for (int i = 0; i < 8; ++i) {
        int m = rowBase + ((i < 4) ? (ty * 4 + i) : (64 + ty * 4 + i - 4));
        #pragma unroll
        for (int jb = 0; jb < 2; ++jb) {
            int j0 = colBase + (jb ? (64 + tx * 4) : (tx * 4));
            float4 bv = *(const float4*)&bias[j0];
            float4 v;
            v.x = acc[i][jb * 4 + 0] + bv.x;
            v.y = acc[i][jb * 4 + 1] + bv.y;
            v.z = acc[i][jb * 4 + 2] + bv.z;
            v.w = acc[i][jb * 4 + 3] + bv.w;
            if (OUT_MODE == 0) {
                *(float4*)&out[(size_t)m * N + j0] = v;
            } else {
                int bb = m >> 11, s = m & 2047;
                int h = j0 >> 6, d = j0 & 63;
                *(float4*)&out[(((size_t)bb * H_ + h) * S_ + s) * DK_ + d] = v;
            }
        }
    }
}

// ---------------- mask bit-pack: one wave -> one 64-bit word -------------------
__global__ __launch_bounds__(256)
void maskpack(const int* __restrict__ mask, unsigned long long* __restrict__ mbits)
{
    int wid  = (blockIdx.x * 256 + threadIdx.x) >> 6;   // word index
    int lane = threadIdx.x & 63;
    int v = mask[(size_t)wid * 64 + lane];
    unsigned long long bal = __ballot(v != 0);
    if (lane == 0) mbits[wid] = bal;
}

// ---------------- MFMA flash attention (f16 2-term split QK^T) ----------------
// scores = mask ? exp(q.k)/8 : -1e9 ; softmax over k ; O = P V
__global__ __launch_bounds__(256)
void flash_mfma(const float* __restrict__ Qh, const float* __restrict__ Kh,
                const float* __restrict__ Vh, const unsigned long long* __restrict__ Mb,
                float* __restrict__ Octx)
{
    // K tile hi/lo f16 [64 kcol][64 dk], XOR-swizzled, pitch 64
    __shared__ __attribute__((aligned(16))) _Float16 KhiS[64 * 64];
    __shared__ __attribute__((aligned(16))) _Float16 KloS[64 * 64];
    // V^T tile f16 [64 d][64 kk], XOR-swizzled, pitch 64
    __shared__ __attribute__((aligned(16))) _Float16 VtS[64 * 64];
    // per-wave P buffer f16 [16 q][72], pitch 72 (b64 reads, 2-way max)
    __shared__ __attribute__((aligned(16))) _Float16 PwS[4][16 * 72];

    const int tid  = threadIdx.x;
    const int lane = tid & 63;
    const int w    = tid >> 6;
    const int lx   = lane & 15;
    const int lg   = lane >> 4;    // 0..3

    // XCD swizzle: 1024 blocks, 8 XCDs, chunk = 128 -> one XCD holds 4 (b,h) groups
    int bid = blockIdx.x;
    int swz = (bid & 7) * 128 + (bid >> 3);
    int qb = swz & 31;
    int h  = (swz >> 5) & 15;
    int b  = swz >> 9;

    const int q0 = qb * 64;
    const size_t bh = (size_t)b * H_ + h;
    const float* Qbase = Qh + bh * S_ * DK_;
    const float* Kbase = Kh + bh * S_ * DK_;
    const float* Vbase = Vh + bh * S_ * DK_;

    // ---- Q A-frags in registers: row = q0 + w*16 + lx, dk = chunk*32 + lg*8 + j
    f16x8 qh0, ql0, qh1, ql1;
    {
        const int qrow = q0 + w * 16 + lx;
        const float* qp = Qbase + (size_t)qrow * DK_ + lg * 8;
        float4 a0 = *(const float4*)qp;
        float4 a1 = *(const float4*)(qp + 4);
        float4 b0 = *(const float4*)(qp + 32);
        float4 b1 = *(const float4*)(qp + 36);
        float t0[8] = {a0.x, a0.y, a0.z, a0.w, a1.x, a1.y, a1.z, a1.w};
        float t1[8] = {b0.x, b0.y, b0.z, b0.w, b1.x, b1.y, b1.z, b1.w};
        #pragma unroll
        for (int j = 0; j < 8; ++j) {
            _Float16 hi = (_Float16)t0[j];
            qh0[j] = hi; ql0[j] = (_Float16)(t0[j] - (float)hi);
            _Float16 hj = (_Float16)t1[j];
            qh1[j] = hj; ql1[j] = (_Float16)(t1[j] - (float)hj);
        }
    }

    f32x4 oacc[4];
    float m_run[4], l_run[4];
    #pragma unroll
    for (int r = 0; r < 4; ++r) { m_run[r] = -INFINITY; l_run[r] = 0.f; }
    #pragma unroll
    for (int dt = 0; dt < 4; ++dt) oacc[dt] = (f32x4){0.f, 0.f, 0.f, 0.f};

    for (int s0 = 0; s0 < S_; s0 += 64) {
        __syncthreads();   // previous tile's frag reads done before restage

        // prefetch mask words (one u64 covers this tile's 64 k-cols)
        unsigned long long mw[4];
        #pragma unroll
        for (int r = 0; r < 4; ++r) {
            int qr = q0 + w * 16 + lg * 4 + r;
            mw[r] = Mb[((size_t)b * S_ + qr) * (S_ / 64) + (s0 >> 6)];
        }

        // ---- stage K (hi/lo split) and V^T, fp32 -> f16, XOR-swizzled
        {
            int r  = tid >> 2;             // 0..63 (kcol for K, kk for V)
            int c0 = (tid & 3) * 16;       // dk / d base
            const float* kp = Kbase + (size_t)(s0 + r) * DK_ + c0;
            float4 k0 = *(const float4*)kp;
            float4 k1 = *(const float4*)(kp + 4);
            float4 k2 = *(const float4*)(kp + 8);
            float4 k3 = *(const float4*)(kp + 12);
            float kv[16] = {k0.x,k0.y,k0.z,k0.w, k1.x,k1.y,k1.z,k1.w,
                            k2.x,k2.y,k2.z,k2.w, k3.x,k3.y,k3.z,k3.w};
            f16x8 hA, hB, lA, lB;
            #pragma unroll
            for (int j = 0; j < 8; ++j) {
                _Float16 hi = (_Float16)kv[j];
                hA[j] = hi; lA[j] = (_Float16)(kv[j] - (float)hi);
                _Float16 hj = (_Float16)kv[8 + j];
                hB[j] = hj; lB[j] = (_Float16)(kv[8 + j] - (float)hj);
            }
            int base = r * 128 + c0 * 2;
            int sw = (r & 7) << 4;
            *(f16x8*)((char*)KhiS + ((base +  0) ^ sw)) = hA;
            *(f16x8*)((char*)KhiS + ((base + 16) ^ sw)) = hB;
            *(f16x8*)((char*)KloS + ((base +  0) ^ sw)) = lA;
            *(f16x8*)((char*)KloS + ((base + 16) ^ sw)) = lB;

            const float* vp = Vbase + (size_t)(s0 + r) * DK_ + c0;
            float4 v0 = *(const float4*)vp;
            float4 v1 = *(const float4*)(vp + 4);
            float4 v2 = *(const float4*)(vp + 8);
            float4 v3 = *(const float4*)(vp + 12);
            float vv[16] = {v0.x,v0.y,v0.z,v0.w, v1.x,v1.y,v1.z,v1.w,
                            v2.x,v2.y,v2.z,v2.w, v3.x,v3.y,v3.z,v3.w};
            #pragma unroll
            for (int i = 0; i < 16; ++i) {
                int d = c0 + i;
                int boff = (d * 128 + r * 2) ^ ((d & 7) << 4);
                *(_Float16*)((char*)VtS + boff) = (_Float16)vv[i];
            }
        }
        __syncthreads();

        // ---- QK^T via 8 MFMAs per col-tile (hh, hl, lh, ll splits), then mask+exp
        float p[4][4];     // [ct][r]
        float tmax[4] = {-1e9f, -1e9f, -1e9f, -1e9f};
        #pragma unroll
        for (int ct = 0; ct < 4; ++ct) {
            int row  = ct * 16 + lx;
            int sw   = (row & 7) << 4;
            int base = row * 128 + lg * 16;
            f16x8 kh0 = *(const f16x8*)((const char*)KhiS + ((base +  0) ^ sw));
            f16x8 kh1 = *(const f16x8*)((const char*)KhiS + ((base + 64) ^ sw));
            f16x8 kl0 = *(const f16x8*)((const char*)KloS + ((base +  0) ^ sw));
            f16x8 kl1 = *(const f16x8*)((const char*)KloS + ((base + 64) ^ sw));
            f32x4 s = (f32x4){0.f, 0.f, 0.f, 0.f};
            s = MFMA16(qh0, kh0, s);
            s = MFMA16(qh1, kh1, s);
            s = MFMA16(qh0, kl0, s);
            s = MFMA16(qh1, kl1, s);
            s = MFMA16(ql0, kh0, s);
            s = MFMA16(ql1, kh1, s);
            s = MFMA16(ql0, kl0, s);
            s = MFMA16(ql1, kl1, s);
            #pragma unroll
            for (int r = 0; r < 4; ++r) {
                float tv = ((mw[r] >> (ct * 16 + lx)) & 1ull)
                             ? __expf(s[r]) * 0.125f : -1e9f;
                p[ct][r] = tv;
                tmax[r] = fmaxf(tmax[r], tv);
            }
        }
        // row max across the 16 lanes of each row group
        #pragma unroll
        for (int m = 1; m < 16; m <<= 1) {
            #pragma unroll
            for (int r = 0; r < 4; ++r)
                tmax[r] = fmaxf(tmax[r], __shfl_xor(tmax[r], m, 64));
        }
        float rs[4], scl[4];
        #pragma unroll
        for (int r = 0; r < 4; ++r) {
            float mn = fmaxf(m_run[r], tmax[r]);
            scl[r] = __expf(m_run[r] - mn);
            m_run[r] = mn;
            float sum = 0.f;
            #pragma unroll
            for (int ct = 0; ct < 4; ++ct) {
                p[ct][r] = __expf(p[ct][r] - mn);
                sum += p[ct][r];
            }
            rs[r] = sum;
            l_run[r] *= scl[r];
        }
        #pragma unroll
        for (int m = 1; m < 16; m <<= 1) {
            #pragma unroll
            for (int r = 0; r < 4; ++r)
                rs[r] += __shfl_xor(rs[r], m, 64);
        }
        #pragma unroll
        for (int r = 0; r < 4; ++r) l_run[r] += rs[r];
        #pragma unroll
        for (int dt = 0; dt < 4; ++dt) {
            #pragma unroll
            for (int r = 0; r < 4; ++r) oacc[dt][r] *= scl[r];
        }

        // ---- P (f32 D-frags) -> f16 per-wave LDS buffer
        _Float16* Pp = &PwS[w][0];
        #pragma unroll
        for (int ct = 0; ct < 4; ++ct)
            #pragma unroll
            for (int r = 0; r < 4; ++r)
                Pp[(lg * 4 + r) * 72 + ct * 16 + lx] = (_Float16)p[ct][r];

        // ---- PV: A-frags from P buffer, B-frags from V^T
        union F8 { f16x8 v; f16x4 h[2]; };
        F8 pa0, pa1;
        {
            int pb = lx * 72 + lg * 8;
            pa0.h[0] = *(const f16x4*)&Pp[pb];
            pa0.h[1] = *(const f16x4*)&Pp[pb + 4];
            pa1.h[0] = *(const f16x4*)&Pp[pb + 32];
            pa1.h[1] = *(const f16x4*)&Pp[pb + 36];
        }
        #pragma unroll
        for (int dt = 0; dt < 4; ++dt) {
            int row  = dt * 16 + lx;
            int sw2  = (row & 7) << 4;
            int vb   = row * 128 + lg * 16;
            f16x8 v0 = *(const f16x8*)((const char*)VtS + ((vb +  0) ^ sw2));
            f16x8 v1 = *(const f16x8*)((const char*)VtS + ((vb + 64) ^ sw2));
            oacc[dt] = MFMA16(pa0.v, v0, oacc[dt]);
            oacc[dt] = MFMA16(pa1.v, v1, oacc[dt]);
        }
    }

    // ---- epilogue: normalize, merge heads
    float inv[4];
    #pragma unroll
    for (int r = 0; r < 4; ++r) inv[r] = 1.0f / l_run[r];
    #pragma unroll
    for (int dt = 0; dt < 4; ++dt) {
        #pragma unroll
        for (int r = 0; r < 4; ++r) {
            int q = q0 + w * 16 + lg * 4 + r;
            Octx[((size_t)b * S_ + q) * D_ + h * DK_ + dt * 16 + lx] =
                oacc[dt][r] * inv[r];
        }
    }
}

extern "C" void kernel_launch(void* const* d_in, const int* in_sizes, int n_in,
                              void* d_out, int out_size, void* d_ws, size_t ws_size,
                              hipStream_t stream)
{
    const float* query = (const float*)d_in[0];
    const float* key_  = (const float*)d_in[1];
    const float* value = (const float*)d_in[2];
    const int*   mask  = (const int*)d_in[3];
    const float* Wq = (const float*)d_in[4];
    const float* bq = (const float*)d_in[5];
    const float* Wk = (const float*)d_in[6];
    const float* bk = (const float*)d_in[7];
    const float* Wv = (const float*)d_in[8];
    const float* bv = (const float*)d_in[9];
    const float* Wo = (const float*)d_in[10];
    const float* bo = (const float*)d_in[11];

    float* ws = (float*)d_ws;
    const size_t hsz = (size_t)B_ * H_ * S_ * DK_;   // 4,194,304 floats
    float* Qh   = ws;
    float* Kh   = Qh + hsz;
    float* Vh   = Kh + hsz;
    float* Octx = Vh + hsz;
    unsigned long long* mbits = (unsigned long long*)(Octx + hsz);  // 1 MiB
    float* out  = (float*)d_out;

    dim3 gg(D_ / 128, M_ / 128);
    sgemm_xwT<1><<<gg, 256, 0, stream>>>(query, Wq, bq, Qh);
    sgemm_xwT<1><<<gg, 256, 0, stream>>>(key_,  Wk, bk, Kh);
    sgemm_xwT<1><<<gg, 256, 0, stream>>>(value, Wv, bv, Vh);

    // pack mask: B*S*S bits = B*S*32 words; one wave per word
    maskpack<<<(B_ * S_ * (S_ / 64) * 64) / 256, 256, 0, stream>>>(mask, mbits);

    flash_mfma<<<B_ * H_ * (S_ / 64), 256, 0, stream>>>(Qh, Kh, Vh, mbits, Octx);

    sgemm_xwT<0><<<gg, 256, 0, stream>>>(Octx, Wo, bo, out);
}

// Round 3
// 344.227 us; speedup vs baseline: 3.3189x; 2.0340x over previous
//
#include <hip/hip_runtime.h>
#include <math.h>

#define B_ 2
#define S_ 2048
#define D_ 1024
#define H_ 16
#define DK_ 64
#define M_ (B_*S_)   // 4096

typedef __attribute__((ext_vector_type(8))) _Float16 f16x8;
typedef __attribute__((ext_vector_type(4))) _Float16 f16x4;
typedef __attribute__((ext_vector_type(4))) float f32x4;

#define MFMA16(a,b,c) __builtin_amdgcn_mfma_f32_16x16x32_f16((a),(b),(c),0,0,0)

__device__ __forceinline__ void gload16(const void* g, void* l) {
    __builtin_amdgcn_global_load_lds(
        (const __attribute__((address_space(1))) unsigned int*)g,
        (__attribute__((address_space(3))) unsigned int*)l, 16, 0, 0);
}

// ---------------- W split pass: Whi/Wlo = f16 split of 64*W ------------------
__global__ __launch_bounds__(256)
void wsplit(const float* __restrict__ Wq, const float* __restrict__ Wk,
            const float* __restrict__ Wv, const float* __restrict__ Wo,
            _Float16* __restrict__ hq, _Float16* __restrict__ lq,
            _Float16* __restrict__ hk, _Float16* __restrict__ lk,
            _Float16* __restrict__ hv, _Float16* __restrict__ ho)
{
    int t = blockIdx.x * 256 + threadIdx.x;     // 2^19 threads, 8 elems each
    int mi = t >> 17;
    int e  = (t & 131071) * 8;
    const float* src = (mi == 0) ? Wq : (mi == 1) ? Wk : (mi == 2) ? Wv : Wo;
    float4 a = *(const float4*)&src[e];
    float4 b = *(const float4*)&src[e + 4];
    float v[8] = {a.x, a.y, a.z, a.w, b.x, b.y, b.z, b.w};
    f16x8 hi, lo;
    #pragma unroll
    for (int j = 0; j < 8; ++j) {
        float s = v[j] * 64.f;                  // pow2 scale: keep lo out of denorms
        _Float16 h = (_Float16)s;
        hi[j] = h; lo[j] = (_Float16)(s - (float)h);
    }
    if (mi == 0)      { *(f16x8*)&hq[e] = hi; *(f16x8*)&lq[e] = lo; }
    else if (mi == 1) { *(f16x8*)&hk[e] = hi; *(f16x8*)&lk[e] = lo; }
    else if (mi == 2) { *(f16x8*)&hv[e] = hi; }
    else              { *(f16x8*)&ho[e] = hi; }
}

// ---------------- mask bit-pack -----------------------------------------------
__global__ __launch_bounds__(256)
void maskpack(const int* __restrict__ mask, unsigned long long* __restrict__ mbits)
{
    int wid  = (blockIdx.x * 256 + threadIdx.x) >> 6;
    int lane = threadIdx.x & 63;
    int v = mask[(size_t)wid * 64 + lane];
    unsigned long long bal = __ballot(v != 0);
    if (lane == 0) mbits[wid] = bal;
}

// ---------------- MFMA GEMM: C = X @ (64*W)^T / 64 + bias ---------------------
// NPROD: 3 = split f16 (hh+hl+lh), 1 = hi only.
// AMODE: 0 = A fp32 (convert in-kernel), 1 = A f16 passthrough.
// OUT_MODE: 0 = fp32 [M][N]; 1 = f16 hi/lo scatter [B][H][S][DK] (lo at +M_*D_);
//           2 = f16 scatter transposed [B][H][DK][S].
template<int NPROD, int AMODE, int OUT_MODE>
__global__ __launch_bounds__(256)
void gemm16(const void* __restrict__ Ap, const _Float16* __restrict__ Bhi,
            const _Float16* __restrict__ Blo, const float* __restrict__ bias,
            void* __restrict__ outp)
{
    __shared__ __attribute__((aligned(16))) _Float16 AhiS[128 * 32];
    __shared__ __attribute__((aligned(16))) _Float16 AloS[NPROD == 3 ? 128 * 32 : 16];
    __shared__ __attribute__((aligned(16))) _Float16 BhiS[128 * 32];
    __shared__ __attribute__((aligned(16))) _Float16 BloS[NPROD == 3 ? 128 * 32 : 16];

    const int tid  = threadIdx.x;
    const int lane = tid & 63, w = tid >> 6;
    const int lx   = lane & 15, lg = lane >> 4;
    const int wm   = w >> 1, wn = w & 1;

    // XCD-chunked swizzle: XCD x gets 4 row-panels x all 8 col-panels
    int gid = blockIdx.x;
    int nid = (gid & 7) * 32 + (gid >> 3);
    const int colBase = (nid & 7) * 128;
    const int rowBase = (nid >> 3) * 128;

    f32x4 acc[4][4];
    #pragma unroll
    for (int i = 0; i < 4; ++i)
        #pragma unroll
        for (int j = 0; j < 4; ++j) acc[i][j] = (f32x4){0.f, 0.f, 0.f, 0.f};

    const int sr = tid >> 1, sh = tid & 1;     // staging row / k-half

    for (int k0 = 0; k0 < D_; k0 += 32) {
        __syncthreads();
        // ---- B tiles via global_load_lds, source chunks pre-swizzled c^(r&3)
        #pragma unroll
        for (int ii = 0; ii < 2; ++ii) {
            int i  = w * 2 + ii;
            int rr = i * 16 + (lane >> 2);
            int cc = (lane & 3) ^ ((lane >> 2) & 3);
            gload16(Bhi + (size_t)(colBase + rr) * D_ + k0 + cc * 8, &BhiS[i * 512]);
            if (NPROD == 3)
                gload16(Blo + (size_t)(colBase + rr) * D_ + k0 + cc * 8, &BloS[i * 512]);
        }
        // ---- A tile: reg-staged
        {
            char* bp = (char*)AhiS + sr * 64;
            int c0 = sh * 2;
            if (AMODE == 0) {
                const float* ap = (const float*)Ap + (size_t)(rowBase + sr) * D_ + k0 + sh * 16;
                float4 x0 = *(const float4*)ap;
                float4 x1 = *(const float4*)(ap + 4);
                float4 x2 = *(const float4*)(ap + 8);
                float4 x3 = *(const float4*)(ap + 12);
                float xv[16] = {x0.x,x0.y,x0.z,x0.w, x1.x,x1.y,x1.z,x1.w,
                                x2.x,x2.y,x2.z,x2.w, x3.x,x3.y,x3.z,x3.w};
                f16x8 hi[2], lo[2];
                #pragma unroll
                for (int j = 0; j < 16; ++j) {
                    _Float16 hv = (_Float16)xv[j];
                    hi[j >> 3][j & 7] = hv;
                    if (NPROD == 3) lo[j >> 3][j & 7] = (_Float16)(xv[j] - (float)hv);
                }
                *(f16x8*)(bp + 16 * ((c0 + 0) ^ (sr & 3))) = hi[0];
                *(f16x8*)(bp + 16 * ((c0 + 1) ^ (sr & 3))) = hi[1];
                if (NPROD == 3) {
                    char* lp = (char*)AloS + sr * 64;
                    *(f16x8*)(lp + 16 * ((c0 + 0) ^ (sr & 3))) = lo[0];
                    *(f16x8*)(lp + 16 * ((c0 + 1) ^ (sr & 3))) = lo[1];
                }
            } else {
                const _Float16* ap = (const _Float16*)Ap + (size_t)(rowBase + sr) * D_ + k0 + sh * 16;
                f16x8 h0 = *(const f16x8*)ap;
                f16x8 h1 = *(const f16x8*)(ap + 8);
                *(f16x8*)(bp + 16 * ((c0 + 0) ^ (sr & 3))) = h0;
                *(f16x8*)(bp + 16 * ((c0 + 1) ^ (sr & 3))) = h1;
            }
        }
        __syncthreads();

        // ---- fragments + MFMA
        f16x8 bh[4], bl[4];
        #pragma unroll
        for (int fj = 0; fj < 4; ++fj) {
            int brow = wn * 64 + fj * 16 + lx;
            bh[fj] = *(const f16x8*)((char*)BhiS + brow * 64 + 16 * (lg ^ (brow & 3)));
            if (NPROD == 3)
                bl[fj] = *(const f16x8*)((char*)BloS + brow * 64 + 16 * (lg ^ (brow & 3)));
        }
        #pragma unroll
        for (int fi = 0; fi < 4; ++fi) {
            int arow = wm * 64 + fi * 16 + lx;
            f16x8 ah = *(const f16x8*)((char*)AhiS + arow * 64 + 16 * (lg ^ (arow & 3)));
            f16x8 al;
            if (NPROD == 3)
                al = *(const f16x8*)((char*)AloS + arow * 64 + 16 * (lg ^ (arow & 3)));
            #pragma unroll
            for (int fj = 0; fj < 4; ++fj) {
                acc[fi][fj] = MFMA16(ah, bh[fj], acc[fi][fj]);
                if (NPROD == 3) {
                    acc[fi][fj] = MFMA16(ah, bl[fj], acc[fi][fj]);
                    acc[fi][fj] = MFMA16(al, bh[fj], acc[fi][fj]);
                }
            }
        }
    }

    // ---- epilogue (acc * 1/64 + bias)
    constexpr float INV = 1.f / 64.f;
    #pragma unroll
    for (int fi = 0; fi < 4; ++fi) {
        #pragma unroll
        for (int fj = 0; fj < 4; ++fj) {
            int n = colBase + wn * 64 + fj * 16 + lx;
            float bv = bias[n];
            if (OUT_MODE == 0) {
                float* out = (float*)outp;
                #pragma unroll
                for (int rr = 0; rr < 4; ++rr) {
                    int m = rowBase + wm * 64 + fi * 16 + lg * 4 + rr;
                    out[(size_t)m * D_ + n] = acc[fi][fj][rr] * INV + bv;
                }
            } else if (OUT_MODE == 1) {
                _Float16* Ohi = (_Float16*)outp;
                _Float16* Olo = Ohi + (size_t)M_ * D_;
                int hh = n >> 6, d = n & 63;
                #pragma unroll
                for (int rr = 0; rr < 4; ++rr) {
                    int m = rowBase + wm * 64 + fi * 16 + lg * 4 + rr;
                    int bb = m >> 11, s = m & 2047;
                    float val = acc[fi][fj][rr] * INV + bv;
                    _Float16 hv = (_Float16)val;
                    size_t o = (((size_t)bb * H_ + hh) * S_ + s) * DK_ + d;
                    Ohi[o] = hv;
                    Olo[o] = (_Float16)(val - (float)hv);
                }
            } else {
                _Float16* Vt = (_Float16*)outp;
                int hh = n >> 6, d = n & 63;
                int m0 = rowBase + wm * 64 + fi * 16 + lg * 4;
                int bb = m0 >> 11, s = m0 & 2047;
                f16x4 pk;
                #pragma unroll
                for (int rr = 0; rr < 4; ++rr)
                    pk[rr] = (_Float16)(acc[fi][fj][rr] * INV + bv);
                *(f16x4*)&Vt[(((size_t)bb * H_ + hh) * DK_ + d) * S_ + s] = pk;
            }
        }
    }
}

// ---------------- MFMA flash attention, all-f16 inputs ------------------------
__global__ __launch_bounds__(256)
void flash_mfma(const _Float16* __restrict__ Qhi, const _Float16* __restrict__ Qlo,
                const _Float16* __restrict__ Khi, const _Float16* __restrict__ Klo,
                const _Float16* __restrict__ Vt, const unsigned long long* __restrict__ Mb,
                _Float16* __restrict__ octx)
{
    __shared__ __attribute__((aligned(16))) _Float16 KhiS[64 * 64];
    __shared__ __attribute__((aligned(16))) _Float16 KloS[64 * 64];
    __shared__ __attribute__((aligned(16))) _Float16 VtS[64 * 64];
    __shared__ __attribute__((aligned(16))) _Float16 PwS[4][16 * 72];

    const int tid  = threadIdx.x;
    const int lane = tid & 63;
    const int w    = tid >> 6;
    const int lx   = lane & 15;
    const int lg   = lane >> 4;

    int bid = blockIdx.x;
    int swz = (bid & 7) * 128 + (bid >> 3);
    int qb = swz & 31;
    int h  = (swz >> 5) & 15;
    int b  = swz >> 9;

    const int q0 = qb * 64;
    const size_t bh = (size_t)b * H_ + h;
    const _Float16* KhiG = Khi + bh * S_ * DK_;
    const _Float16* KloG = Klo + bh * S_ * DK_;
    const _Float16* VtG  = Vt  + bh * DK_ * S_;

    // Q fragments (f16 hi/lo, direct from global)
    const int qrow = q0 + w * 16 + lx;
    const _Float16* qph = Qhi + bh * S_ * DK_ + (size_t)qrow * DK_ + lg * 8;
    const _Float16* qpl = Qlo + bh * S_ * DK_ + (size_t)qrow * DK_ + lg * 8;
    f16x8 qh0 = *(const f16x8*)qph;
    f16x8 qh1 = *(const f16x8*)(qph + 32);
    f16x8 ql0 = *(const f16x8*)qpl;
    f16x8 ql1 = *(const f16x8*)(qpl + 32);

    f32x4 oacc[4];
    float m_run[4], l_run[4];
    #pragma unroll
    for (int r = 0; r < 4; ++r) { m_run[r] = -INFINITY; l_run[r] = 0.f; }
    #pragma unroll
    for (int dt = 0; dt < 4; ++dt) oacc[dt] = (f32x4){0.f, 0.f, 0.f, 0.f};

    for (int s0 = 0; s0 < S_; s0 += 64) {
        __syncthreads();

        unsigned long long mw[4];
        #pragma unroll
        for (int r = 0; r < 4; ++r) {
            int qr = q0 + w * 16 + lg * 4 + r;
            mw[r] = Mb[((size_t)b * S_ + qr) * (S_ / 64) + (s0 >> 6)];
        }

        // ---- stage K hi/lo and V^T via global_load_lds (source pre-swizzled)
        #pragma unroll
        for (int ii = 0; ii < 2; ++ii) {
            int i  = w * 2 + ii;
            int rr = i * 8 + (lane >> 3);
            int cc = (lane & 7) ^ (lane >> 3);
            gload16(KhiG + (size_t)(s0 + rr) * DK_ + cc * 8, &KhiS[i * 512]);
            gload16(KloG + (size_t)(s0 + rr) * DK_ + cc * 8, &KloS[i * 512]);
            gload16(VtG + (size_t)rr * S_ + s0 + cc * 8, &VtS[i * 512]);
        }
        __syncthreads();

        // ---- QK^T: 6 MFMAs per col-tile (hh0,hh1,hl0,hl1,lh0,lh1)
        float p[4][4];
        float tmax[4] = {-1e9f, -1e9f, -1e9f, -1e9f};
        #pragma unroll
        for (int ct = 0; ct < 4; ++ct) {
            int row  = ct * 16 + lx;
            int sw   = (row & 7) << 4;
            int base = row * 128 + lg * 16;
            f16x8 kh0 = *(const f16x8*)((const char*)KhiS + ((base +  0) ^ sw));
            f16x8 kh1 = *(const f16x8*)((const char*)KhiS + ((base + 64) ^ sw));
            f16x8 kl0 = *(const f16x8*)((const char*)KloS + ((base +  0) ^ sw));
            f16x8 kl1 = *(const f16x8*)((const char*)KloS + ((base + 64) ^ sw));
            f32x4 s = (f32x4){0.f, 0.f, 0.f, 0.f};
            s = MFMA16(qh0, kh0, s);
            s = MFMA16(qh1, kh1, s);
            s = MFMA16(qh0, kl0, s);
            s = MFMA16(qh1, kl1, s);
            s = MFMA16(ql0, kh0, s);
            s = MFMA16(ql1, kh1, s);
            #pragma unroll
            for (int r = 0; r < 4; ++r) {
                float tv = ((mw[r] >> (ct * 16 + lx)) & 1ull)
                             ? __expf(s[r]) * 0.125f : -1e9f;
                p[ct][r] = tv;
                tmax[r] = fmaxf(tmax[r], tv);
            }
        }
        #pragma unroll
        for (int m = 1; m < 16; m <<= 1) {
            #pragma unroll
            for (int r = 0; r < 4; ++r)
                tmax[r] = fmaxf(tmax[r], __shfl_xor(tmax[r], m, 64));
        }
        float rs[4], scl[4];
        #pragma unroll
        for (int r = 0; r < 4; ++r) {
            float mn = fmaxf(m_run[r], tmax[r]);
            scl[r] = __expf(m_run[r] - mn);
            m_run[r] = mn;
            float sum = 0.f;
            #pragma unroll
            for (int ct = 0; ct < 4; ++ct) {
                p[ct][r] = __expf(p[ct][r] - mn);
                sum += p[ct][r];
            }
            rs[r] = sum;
            l_run[r] *= scl[r];
        }
        #pragma unroll
        for (int m = 1; m < 16; m <<= 1) {
            #pragma unroll
            for (int r = 0; r < 4; ++r)
                rs[r] += __shfl_xor(rs[r], m, 64);
        }
        #pragma unroll
        for (int r = 0; r < 4; ++r) l_run[r] += rs[r];
        #pragma unroll
        for (int dt = 0; dt < 4; ++dt) {
            #pragma unroll
            for (int r = 0; r < 4; ++r) oacc[dt][r] *= scl[r];
        }

        // ---- P -> per-wave LDS f16 buffer
        _Float16* Pp = &PwS[w][0];
        #pragma unroll
        for (int ct = 0; ct < 4; ++ct)
            #pragma unroll
            for (int r = 0; r < 4; ++r)
                Pp[(lg * 4 + r) * 72 + ct * 16 + lx] = (_Float16)p[ct][r];

        // ---- PV
        union F8 { f16x8 v; f16x4 hh[2]; };
        F8 pa0, pa1;
        {
            int pb = lx * 72 + lg * 8;
            pa0.hh[0] = *(const f16x4*)&Pp[pb];
            pa0.hh[1] = *(const f16x4*)&Pp[pb + 4];
            pa1.hh[0] = *(const f16x4*)&Pp[pb + 32];
            pa1.hh[1] = *(const f16x4*)&Pp[pb + 36];
        }
        #pragma unroll
        for (int dt = 0; dt < 4; ++dt) {
            int row  = dt * 16 + lx;
            int sw2  = (row & 7) << 4;
            int vb   = row * 128 + lg * 16;
            f16x8 v0 = *(const f16x8*)((const char*)VtS + ((vb +  0) ^ sw2));
            f16x8 v1 = *(const f16x8*)((const char*)VtS + ((vb + 64) ^ sw2));
            oacc[dt] = MFMA16(pa0.v, v0, oacc[dt]);
            oacc[dt] = MFMA16(pa1.v, v1, oacc[dt]);
        }
    }

    float inv[4];
    #pragma unroll
    for (int r = 0; r < 4; ++r) inv[r] = 1.0f / l_run[r];
    #pragma unroll
    for (int dt = 0; dt < 4; ++dt) {
        #pragma unroll
        for (int r = 0; r < 4; ++r) {
            int q = q0 + w * 16 + lg * 4 + r;
            octx[((size_t)b * S_ + q) * D_ + h * DK_ + dt * 16 + lx] =
                (_Float16)(oacc[dt][r] * inv[r]);
        }
    }
}

extern "C" void kernel_launch(void* const* d_in, const int* in_sizes, int n_in,
                              void* d_out, int out_size, void* d_ws, size_t ws_size,
                              hipStream_t stream)
{
    const float* query = (const float*)d_in[0];
    const float* key_  = (const float*)d_in[1];
    const float* value = (const float*)d_in[2];
    const int*   mask  = (const int*)d_in[3];
    const float* Wq = (const float*)d_in[4];
    const float* bq = (const float*)d_in[5];
    const float* Wk = (const float*)d_in[6];
    const float* bk = (const float*)d_in[7];
    const float* Wv = (const float*)d_in[8];
    const float* bv = (const float*)d_in[9];
    const float* Wo = (const float*)d_in[10];
    const float* bo = (const float*)d_in[11];

    char* p = (char*)d_ws;
    unsigned long long* mbits = (unsigned long long*)p;  p += (size_t)1 << 20;
    _Float16* WhiQ = (_Float16*)p;  p += (size_t)2 << 20;
    _Float16* WloQ = (_Float16*)p;  p += (size_t)2 << 20;
    _Float16* WhiK = (_Float16*)p;  p += (size_t)2 << 20;
    _Float16* WloK = (_Float16*)p;  p += (size_t)2 << 20;
    _Float16* WhiV = (_Float16*)p;  p += (size_t)2 << 20;
    _Float16* WhiO = (_Float16*)p;  p += (size_t)2 << 20;
    _Float16* Qhi  = (_Float16*)p;  p += (size_t)8 << 20;   // Qlo follows at +4M elems
    _Float16* Qlo  = (_Float16*)p;  p += (size_t)8 << 20;
    _Float16* Khi  = (_Float16*)p;  p += (size_t)8 << 20;
    _Float16* Klo  = (_Float16*)p;  p += (size_t)8 << 20;
    _Float16* VtW  = (_Float16*)p;  p += (size_t)8 << 20;
    _Float16* octx = (_Float16*)p;  p += (size_t)8 << 20;
    float* out = (float*)d_out;

    maskpack<<<(B_ * S_ * (S_ / 64) * 64) / 256, 256, 0, stream>>>(mask, mbits);
    wsplit<<<2048, 256, 0, stream>>>(Wq, Wk, Wv, Wo,
                                     WhiQ, WloQ, WhiK, WloK, WhiV, WhiO);

    gemm16<3, 0, 1><<<256, 256, 0, stream>>>(query, WhiQ, WloQ, bq, Qhi);
    gemm16<3, 0, 1><<<256, 256, 0, stream>>>(key_,  WhiK, WloK, bk, Khi);
    gemm16<1, 0, 2><<<256, 256, 0, stream>>>(value, WhiV, nullptr, bv, VtW);

    flash_mfma<<<B_ * H_ * (S_ / 64), 256, 0, stream>>>(Qhi, Qlo, Khi, Klo, VtW,
                                                        mbits, octx);

    gemm16<1, 1, 0><<<256, 256, 0, stream>>>(octx, WhiO, nullptr, bo, out);
}

// Round 5
// 295.012 us; speedup vs baseline: 3.8726x; 1.1668x over previous
//
#include <hip/hip_runtime.h>
#include <math.h>

#define B_ 2
#define S_ 2048
#define D_ 1024
#define H_ 16
#define DK_ 64
#define M_ (B_*S_)   // 4096

typedef __attribute__((ext_vector_type(8))) _Float16 f16x8;
typedef __attribute__((ext_vector_type(4))) _Float16 f16x4;
typedef __attribute__((ext_vector_type(2))) __fp16 fp16x2;
typedef __attribute__((ext_vector_type(4))) float f32x4;

#define MFMA16(a,b,c) __builtin_amdgcn_mfma_f32_16x16x32_f16((a),(b),(c),0,0,0)

__device__ __forceinline__ void gload16(const void* g, void* l) {
    __builtin_amdgcn_global_load_lds(
        (const __attribute__((address_space(1))) unsigned int*)g,
        (__attribute__((address_space(3))) unsigned int*)l, 16, 0, 0);
}

// ---------------- W split pass: Whi/Wlo = f16 split of 64*W ------------------
__global__ __launch_bounds__(256)
void wsplit(const float* __restrict__ Wq, const float* __restrict__ Wk,
            const float* __restrict__ Wv, const float* __restrict__ Wo,
            _Float16* __restrict__ hq, _Float16* __restrict__ lq,
            _Float16* __restrict__ hk, _Float16* __restrict__ lk,
            _Float16* __restrict__ hv, _Float16* __restrict__ ho)
{
    int t = blockIdx.x * 256 + threadIdx.x;
    int mi = t >> 17;
    int e  = (t & 131071) * 8;
    const float* src = (mi == 0) ? Wq : (mi == 1) ? Wk : (mi == 2) ? Wv : Wo;
    float4 a = *(const float4*)&src[e];
    float4 b = *(const float4*)&src[e + 4];
    float v[8] = {a.x, a.y, a.z, a.w, b.x, b.y, b.z, b.w};
    f16x8 hi, lo;
    #pragma unroll
    for (int j = 0; j < 8; ++j) {
        float s = v[j] * 64.f;                  // pow2 scale: keep lo out of denorms
        _Float16 h = (_Float16)s;
        hi[j] = h; lo[j] = (_Float16)(s - (float)h);
    }
    if (mi == 0)      { *(f16x8*)&hq[e] = hi; *(f16x8*)&lq[e] = lo; }
    else if (mi == 1) { *(f16x8*)&hk[e] = hi; *(f16x8*)&lk[e] = lo; }
    else if (mi == 2) { *(f16x8*)&hv[e] = hi; }
    else              { *(f16x8*)&ho[e] = hi; }
}

// ---------------- mask bit-pack -----------------------------------------------
__global__ __launch_bounds__(256)
void maskpack(const int* __restrict__ mask, unsigned long long* __restrict__ mbits)
{
    int wid  = (blockIdx.x * 256 + threadIdx.x) >> 6;
    int lane = threadIdx.x & 63;
    int v = mask[(size_t)wid * 64 + lane];
    unsigned long long bal = __ballot(v != 0);
    if (lane == 0) mbits[wid] = bal;
}

// ---------------- MFMA GEMM: C = X @ (64*W)^T / 64 + bias ---------------------
template<int NPROD, int AMODE, int OUT_MODE>
__global__ __launch_bounds__(256)
void gemm16(const void* __restrict__ Ap, const _Float16* __restrict__ Bhi,
            const _Float16* __restrict__ Blo, const float* __restrict__ bias,
            void* __restrict__ outp)
{
    __shared__ __attribute__((aligned(16))) _Float16 AhiS[128 * 32];
    __shared__ __attribute__((aligned(16))) _Float16 AloS[NPROD == 3 ? 128 * 32 : 16];
    __shared__ __attribute__((aligned(16))) _Float16 BhiS[128 * 32];
    __shared__ __attribute__((aligned(16))) _Float16 BloS[NPROD == 3 ? 128 * 32 : 16];

    const int tid  = threadIdx.x;
    const int lane = tid & 63, w = tid >> 6;
    const int lx   = lane & 15, lg = lane >> 4;
    const int wm   = w >> 1, wn = w & 1;

    int gid = blockIdx.x;
    int nid = (gid & 7) * 32 + (gid >> 3);
    const int colBase = (nid & 7) * 128;
    const int rowBase = (nid >> 3) * 128;

    f32x4 acc[4][4];
    #pragma unroll
    for (int i = 0; i < 4; ++i)
        #pragma unroll
        for (int j = 0; j < 4; ++j) acc[i][j] = (f32x4){0.f, 0.f, 0.f, 0.f};

    const int sr = tid >> 1, sh = tid & 1;

    for (int k0 = 0; k0 < D_; k0 += 32) {
        __syncthreads();
        #pragma unroll
        for (int ii = 0; ii < 2; ++ii) {
            int i  = w * 2 + ii;
            int rr = i * 16 + (lane >> 2);
            int cc = (lane & 3) ^ ((lane >> 2) & 3);
            gload16(Bhi + (size_t)(colBase + rr) * D_ + k0 + cc * 8, &BhiS[i * 512]);
            if (NPROD == 3)
                gload16(Blo + (size_t)(colBase + rr) * D_ + k0 + cc * 8, &BloS[i * 512]);
        }
        {
            char* bp = (char*)AhiS + sr * 64;
            int c0 = sh * 2;
            if (AMODE == 0) {
                const float* ap = (const float*)Ap + (size_t)(rowBase + sr) * D_ + k0 + sh * 16;
                float4 x0 = *(const float4*)ap;
                float4 x1 = *(const float4*)(ap + 4);
                float4 x2 = *(const float4*)(ap + 8);
                float4 x3 = *(const float4*)(ap + 12);
                float xv[16] = {x0.x,x0.y,x0.z,x0.w, x1.x,x1.y,x1.z,x1.w,
                                x2.x,x2.y,x2.z,x2.w, x3.x,x3.y,x3.z,x3.w};
                f16x8 hi[2], lo[2];
                #pragma unroll
                for (int j = 0; j < 16; ++j) {
                    _Float16 hv = (_Float16)xv[j];
                    hi[j >> 3][j & 7] = hv;
                    if (NPROD == 3) lo[j >> 3][j & 7] = (_Float16)(xv[j] - (float)hv);
                }
                *(f16x8*)(bp + 16 * ((c0 + 0) ^ (sr & 3))) = hi[0];
                *(f16x8*)(bp + 16 * ((c0 + 1) ^ (sr & 3))) = hi[1];
                if (NPROD == 3) {
                    char* lp = (char*)AloS + sr * 64;
                    *(f16x8*)(lp + 16 * ((c0 + 0) ^ (sr & 3))) = lo[0];
                    *(f16x8*)(lp + 16 * ((c0 + 1) ^ (sr & 3))) = lo[1];
                }
            } else {
                const _Float16* ap = (const _Float16*)Ap + (size_t)(rowBase + sr) * D_ + k0 + sh * 16;
                f16x8 h0 = *(const f16x8*)ap;
                f16x8 h1 = *(const f16x8*)(ap + 8);
                *(f16x8*)(bp + 16 * ((c0 + 0) ^ (sr & 3))) = h0;
                *(f16x8*)(bp + 16 * ((c0 + 1) ^ (sr & 3))) = h1;
            }
        }
        __syncthreads();

        f16x8 bh[4], bl[4];
        #pragma unroll
        for (int fj = 0; fj < 4; ++fj) {
            int brow = wn * 64 + fj * 16 + lx;
            bh[fj] = *(const f16x8*)((char*)BhiS + brow * 64 + 16 * (lg ^ (brow & 3)));
            if (NPROD == 3)
                bl[fj] = *(const f16x8*)((char*)BloS + brow * 64 + 16 * (lg ^ (brow & 3)));
        }
        #pragma unroll
        for (int fi = 0; fi < 4; ++fi) {
            int arow = wm * 64 + fi * 16 + lx;
            f16x8 ah = *(const f16x8*)((char*)AhiS + arow * 64 + 16 * (lg ^ (arow & 3)));
            f16x8 al;
            if (NPROD == 3)
                al = *(const f16x8*)((char*)AloS + arow * 64 + 16 * (lg ^ (arow & 3)));
            #pragma unroll
            for (int fj = 0; fj < 4; ++fj) {
                acc[fi][fj] = MFMA16(ah, bh[fj], acc[fi][fj]);
                if (NPROD == 3) {
                    acc[fi][fj] = MFMA16(ah, bl[fj], acc[fi][fj]);
                    acc[fi][fj] = MFMA16(al, bh[fj], acc[fi][fj]);
                }
            }
        }
    }

    constexpr float INV = 1.f / 64.f;
    #pragma unroll
    for (int fi = 0; fi < 4; ++fi) {
        #pragma unroll
        for (int fj = 0; fj < 4; ++fj) {
            int n = colBase + wn * 64 + fj * 16 + lx;
            float bv = bias[n];
            if (OUT_MODE == 0) {
                float* out = (float*)outp;
                #pragma unroll
                for (int rr = 0; rr < 4; ++rr) {
                    int m = rowBase + wm * 64 + fi * 16 + lg * 4 + rr;
                    out[(size_t)m * D_ + n] = acc[fi][fj][rr] * INV + bv;
                }
            } else if (OUT_MODE == 1) {
                _Float16* Ohi = (_Float16*)outp;
                _Float16* Olo = Ohi + (size_t)M_ * D_;
                int hh = n >> 6, d = n & 63;
                #pragma unroll
                for (int rr = 0; rr < 4; ++rr) {
                    int m = rowBase + wm * 64 + fi * 16 + lg * 4 + rr;
                    int bb = m >> 11, s = m & 2047;
                    float val = acc[fi][fj][rr] * INV + bv;
                    _Float16 hv = (_Float16)val;
                    size_t o = (((size_t)bb * H_ + hh) * S_ + s) * DK_ + d;
                    Ohi[o] = hv;
                    Olo[o] = (_Float16)(val - (float)hv);
                }
            } else {
                _Float16* Vt = (_Float16*)outp;
                int hh = n >> 6, d = n & 63;
                int m0 = rowBase + wm * 64 + fi * 16 + lg * 4;
                int bb = m0 >> 11, s = m0 & 2047;
                f16x4 pk;
                #pragma unroll
                for (int rr = 0; rr < 4; ++rr)
                    pk[rr] = (_Float16)(acc[fi][fj][rr] * INV + bv);
                *(f16x4*)&Vt[(((size_t)bb * H_ + hh) * DK_ + d) * S_ + s] = pk;
            }
        }
    }
}

// ---------------- MFMA flash attention v3: swapped QK^T, lane-local softmax ---
// scores = mask ? exp(q.k)/8 : -1e9 ; softmax over k ; octx = (P V) merged heads
__global__ __launch_bounds__(256)
void flash_mfma(const _Float16* __restrict__ Qhi, const _Float16* __restrict__ Qlo,
                const _Float16* __restrict__ Khi, const _Float16* __restrict__ Klo,
                const _Float16* __restrict__ Vt, const unsigned long long* __restrict__ Mb,
                _Float16* __restrict__ octx)
{
    __shared__ __attribute__((aligned(16))) _Float16 KhiS[64 * 64];
    __shared__ __attribute__((aligned(16))) _Float16 KloS[64 * 64];
    __shared__ __attribute__((aligned(16))) _Float16 VtS[64 * 64];
    __shared__ __attribute__((aligned(16))) _Float16 PwS[4][32 * 64];  // per-wave P

    const int tid  = threadIdx.x;
    const int lane = tid & 63;
    const int w    = tid >> 6;
    const int lx   = lane & 15;
    const int lg   = lane >> 4;

    // XCD swizzle over 512 blocks (64 per XCD)
    int bid = blockIdx.x;
    int swz = (bid & 7) * 64 + (bid >> 3);
    int qb = swz & 15;
    int h  = (swz >> 4) & 15;
    int b  = swz >> 8;

    const int q0 = qb * 128;
    const size_t bh = (size_t)b * H_ + h;
    const _Float16* KhiG = Khi + bh * S_ * DK_;
    const _Float16* KloG = Klo + bh * S_ * DK_;
    const _Float16* VtG  = Vt  + bh * DK_ * S_;

    // ---- Q fragments (B-operand): qrow = q0 + w*32 + qg*16 + lx, dk = lg*8+j
    f16x8 qh[2][2], ql[2][2];
    #pragma unroll
    for (int qg = 0; qg < 2; ++qg) {
        int qrow = q0 + w * 32 + qg * 16 + lx;
        const _Float16* ph = Qhi + bh * S_ * DK_ + (size_t)qrow * DK_ + lg * 8;
        const _Float16* pl = Qlo + bh * S_ * DK_ + (size_t)qrow * DK_ + lg * 8;
        qh[qg][0] = *(const f16x8*)ph;
        qh[qg][1] = *(const f16x8*)(ph + 32);
        ql[qg][0] = *(const f16x8*)pl;
        ql[qg][1] = *(const f16x8*)(pl + 32);
    }

    f32x4 oacc[2][4];
    float m_run[2], l_run[2];
    #pragma unroll
    for (int qg = 0; qg < 2; ++qg) {
        m_run[qg] = -1e30f; l_run[qg] = 0.f;
        #pragma unroll
        for (int dt = 0; dt < 4; ++dt) oacc[qg][dt] = (f32x4){0.f, 0.f, 0.f, 0.f};
    }

    char* Pw = (char*)&PwS[w][0];

    for (int s0 = 0; s0 < S_; s0 += 64) {
        __syncthreads();   // prior tile's LDS reads done

        // stage K hi/lo + V^T (pre-swizzled source chunks, linear LDS dest)
        #pragma unroll
        for (int ii = 0; ii < 2; ++ii) {
            int i  = w * 2 + ii;
            int rr = i * 8 + (lane >> 3);
            int cc = (lane & 7) ^ (lane >> 3);
            gload16(KhiG + (size_t)(s0 + rr) * DK_ + cc * 8, &KhiS[i * 512]);
            gload16(KloG + (size_t)(s0 + rr) * DK_ + cc * 8, &KloS[i * 512]);
            gload16(VtG + (size_t)rr * S_ + s0 + cc * 8, &VtS[i * 512]);
        }
        unsigned long long mw[2];
        #pragma unroll
        for (int qg = 0; qg < 2; ++qg) {
            int qr = q0 + w * 32 + qg * 16 + lx;
            mw[qg] = Mb[((size_t)b * S_ + qr) * (S_ / 64) + (s0 >> 6)];
        }
        __syncthreads();

        // ---- swapped QK^T: s^T[kcol][qrow]; lane: qrow=lx(+qg*16), kcol=ct*16+lg*4+r
        float sv[2][4][4];
        #pragma unroll
        for (int ct = 0; ct < 4; ++ct) {
            int row  = ct * 16 + lx;
            int sw   = (row & 7) << 4;
            int base = row * 128 + lg * 16;
            f16x8 kh0 = *(const f16x8*)((const char*)KhiS + ((base +  0) ^ sw));
            f16x8 kh1 = *(const f16x8*)((const char*)KhiS + ((base + 64) ^ sw));
            f16x8 kl0 = *(const f16x8*)((const char*)KloS + ((base +  0) ^ sw));
            f16x8 kl1 = *(const f16x8*)((const char*)KloS + ((base + 64) ^ sw));
            #pragma unroll
            for (int qg = 0; qg < 2; ++qg) {
                f32x4 s = (f32x4){0.f, 0.f, 0.f, 0.f};
                s = MFMA16(kh0, qh[qg][0], s);
                s = MFMA16(kh1, qh[qg][1], s);
                s = MFMA16(kl0, qh[qg][0], s);
                s = MFMA16(kl1, qh[qg][1], s);
                s = MFMA16(kh0, ql[qg][0], s);
                s = MFMA16(kh1, ql[qg][1], s);
                #pragma unroll
                for (int r = 0; r < 4; ++r) sv[qg][ct][r] = s[r];
            }
        }

        // ---- per-qgroup softmax (lane-local row state)
        #pragma unroll
        for (int qg = 0; qg < 2; ++qg) {
            unsigned long long ms = mw[qg] >> (lg * 4);
            float tv[16];
            #pragma unroll
            for (int ct = 0; ct < 4; ++ct)
                #pragma unroll
                for (int r = 0; r < 4; ++r) {
                    float e = __expf(sv[qg][ct][r] - 2.0794415416798357f); // exp(s)/8
                    tv[ct * 4 + r] = ((ms >> (ct * 16 + r)) & 1ull) ? e : -1e30f;
                }
            float m01 = fmaxf(fmaxf(tv[0], tv[1]), fmaxf(tv[2], tv[3]));
            float m23 = fmaxf(fmaxf(tv[4], tv[5]), fmaxf(tv[6], tv[7]));
            float m45 = fmaxf(fmaxf(tv[8], tv[9]), fmaxf(tv[10], tv[11]));
            float m67 = fmaxf(fmaxf(tv[12], tv[13]), fmaxf(tv[14], tv[15]));
            float tmax = fmaxf(fmaxf(m01, m23), fmaxf(m45, m67));
            tmax = fmaxf(tmax, __shfl_xor(tmax, 16));
            tmax = fmaxf(tmax, __shfl_xor(tmax, 32));

            if (__any(tmax > m_run[qg])) {       // rescale needed (rare after warmup)
                float mn = fmaxf(m_run[qg], tmax);
                float scl = __expf(m_run[qg] - mn);
                m_run[qg] = mn;
                l_run[qg] *= scl;
                #pragma unroll
                for (int dt = 0; dt < 4; ++dt)
                    #pragma unroll
                    for (int r = 0; r < 4; ++r) oacc[qg][dt][r] *= scl;
            }
            float mr = m_run[qg];
            float pp[16], sum = 0.f;
            #pragma unroll
            for (int i = 0; i < 16; ++i) {
                pp[i] = __expf(tv[i] - mr);
                sum += pp[i];
            }
            sum += __shfl_xor(sum, 16);
            sum += __shfl_xor(sum, 32);
            l_run[qg] += sum;

            // pack P pairs (k-adjacent) -> swizzled per-wave buffer
            int prow = qg * 16 + lx;
            int psw  = (prow & 7) << 4;
            #pragma unroll
            for (int ct = 0; ct < 4; ++ct) {
                fp16x2 a = __builtin_amdgcn_cvt_pkrtz(pp[ct * 4 + 0], pp[ct * 4 + 1]);
                fp16x2 c = __builtin_amdgcn_cvt_pkrtz(pp[ct * 4 + 2], pp[ct * 4 + 3]);
                unsigned int au, cu;
                __builtin_memcpy(&au, &a, 4);
                __builtin_memcpy(&cu, &c, 4);
                int off = prow * 128 + ct * 32 + lg * 8;
                *(unsigned int*)(Pw + ((off + 0) ^ psw)) = au;
                *(unsigned int*)(Pw + ((off + 4) ^ psw)) = cu;
            }
        }

        // ---- PV as O^T = V^T . P^T : A = Vt frags, B = P frags
        f16x8 pa[2][2];
        #pragma unroll
        for (int qg = 0; qg < 2; ++qg) {
            int prow = qg * 16 + lx;
            int psw  = (prow & 7) << 4;
            int pb   = prow * 128 + lg * 16;
            pa[qg][0] = *(const f16x8*)(Pw + ((pb +  0) ^ psw));
            pa[qg][1] = *(const f16x8*)(Pw + ((pb + 64) ^ psw));
        }
        #pragma unroll
        for (int dt = 0; dt < 4; ++dt) {
            int vrow = dt * 16 + lx;
            int vs   = (vrow & 7) << 4;
            int vb   = vrow * 128 + lg * 16;
            f16x8 v0 = *(const f16x8*)((const char*)VtS + ((vb +  0) ^ vs));
            f16x8 v1 = *(const f16x8*)((const char*)VtS + ((vb + 64) ^ vs));
            #pragma unroll
            for (int qg = 0; qg < 2; ++qg) {
                oacc[qg][dt] = MFMA16(v0, pa[qg][0], oacc[qg][dt]);
                oacc[qg][dt] = MFMA16(v1, pa[qg][1], oacc[qg][dt]);
            }
        }
    }

    // ---- epilogue: O^T frag -> octx[b][s][h*64+d], d = dt*16+lg*4+r
    #pragma unroll
    for (int qg = 0; qg < 2; ++qg) {
        float inv = 1.0f / l_run[qg];
        int qrow = q0 + w * 32 + qg * 16 + lx;
        #pragma unroll
        for (int dt = 0; dt < 4; ++dt) {
            f16x4 o;
            #pragma unroll
            for (int r = 0; r < 4; ++r) o[r] = (_Float16)(oacc[qg][dt][r] * inv);
            *(f16x4*)&octx[((size_t)b * S_ + qrow) * D_ + h * DK_ + dt * 16 + lg * 4] = o;
        }
    }
}

extern "C" void kernel_launch(void* const* d_in, const int* in_sizes, int n_in,
                              void* d_out, int out_size, void* d_ws, size_t ws_size,
                              hipStream_t stream)
{
    const float* query = (const float*)d_in[0];
    const float* key_  = (const float*)d_in[1];
    const float* value = (const float*)d_in[2];
    const int*   mask  = (const int*)d_in[3];
    const float* Wq = (const float*)d_in[4];
    const float* bq = (const float*)d_in[5];
    const float* Wk = (const float*)d_in[6];
    const float* bk = (const float*)d_in[7];
    const float* Wv = (const float*)d_in[8];
    const float* bv = (const float*)d_in[9];
    const float* Wo = (const float*)d_in[10];
    const float* bo = (const float*)d_in[11];

    char* p = (char*)d_ws;
    unsigned long long* mbits = (unsigned long long*)p;  p += (size_t)1 << 20;
    _Float16* WhiQ = (_Float16*)p;  p += (size_t)2 << 20;
    _Float16* WloQ = (_Float16*)p;  p += (size_t)2 << 20;
    _Float16* WhiK = (_Float16*)p;  p += (size_t)2 << 20;
    _Float16* WloK = (_Float16*)p;  p += (size_t)2 << 20;
    _Float16* WhiV = (_Float16*)p;  p += (size_t)2 << 20;
    _Float16* WhiO = (_Float16*)p;  p += (size_t)2 << 20;
    _Float16* Qhi  = (_Float16*)p;  p += (size_t)8 << 20;
    _Float16* Qlo  = (_Float16*)p;  p += (size_t)8 << 20;
    _Float16* Khi  = (_Float16*)p;  p += (size_t)8 << 20;
    _Float16* Klo  = (_Float16*)p;  p += (size_t)8 << 20;
    _Float16* VtW  = (_Float16*)p;  p += (size_t)8 << 20;
    _Float16* octx = (_Float16*)p;  p += (size_t)8 << 20;
    float* out = (float*)d_out;

    maskpack<<<(B_ * S_ * (S_ / 64) * 64) / 256, 256, 0, stream>>>(mask, mbits);
    wsplit<<<2048, 256, 0, stream>>>(Wq, Wk, Wv, Wo,
                                     WhiQ, WloQ, WhiK, WloK, WhiV, WhiO);

    gemm16<3, 0, 1><<<256, 256, 0, stream>>>(query, WhiQ, WloQ, bq, Qhi);
    gemm16<3, 0, 1><<<256, 256, 0, stream>>>(key_,  WhiK, WloK, bk, Khi);
    gemm16<1, 0, 2><<<256, 256, 0, stream>>>(value, WhiV, nullptr, bv, VtW);

    flash_mfma<<<512, 256, 0, stream>>>(Qhi, Qlo, Khi, Klo, VtW, mbits, octx);

    gemm16<1, 1, 0><<<256, 256, 0, stream>>>(octx, WhiO, nullptr, bo, out);
}

// Round 6
// 225.059 us; speedup vs baseline: 5.0763x; 1.3108x over previous
//
#include <hip/hip_runtime.h>
#include <math.h>

#define B_ 2
#define S_ 2048
#define D_ 1024
#define H_ 16
#define DK_ 64
#define M_ (B_*S_)   // 4096

typedef __attribute__((ext_vector_type(8))) _Float16 f16x8;
typedef __attribute__((ext_vector_type(4))) _Float16 f16x4;
typedef __attribute__((ext_vector_type(2))) __fp16 fp16x2;
typedef __attribute__((ext_vector_type(4))) float f32x4;

#define MFMA16(a,b,c) __builtin_amdgcn_mfma_f32_16x16x32_f16((a),(b),(c),0,0,0)

__device__ __forceinline__ void gload16(const void* g, void* l) {
    __builtin_amdgcn_global_load_lds(
        (const __attribute__((address_space(1))) unsigned int*)g,
        (__attribute__((address_space(3))) unsigned int*)l, 16, 0, 0);
}

// ---------------- W split pass: Whi/Wlo = f16 split of 64*W ------------------
__global__ __launch_bounds__(256)
void wsplit(const float* __restrict__ Wq, const float* __restrict__ Wk,
            const float* __restrict__ Wv, const float* __restrict__ Wo,
            _Float16* __restrict__ hq, _Float16* __restrict__ lq,
            _Float16* __restrict__ hk, _Float16* __restrict__ lk,
            _Float16* __restrict__ hv, _Float16* __restrict__ ho)
{
    int t = blockIdx.x * 256 + threadIdx.x;
    int mi = t >> 17;
    int e  = (t & 131071) * 8;
    const float* src = (mi == 0) ? Wq : (mi == 1) ? Wk : (mi == 2) ? Wv : Wo;
    float4 a = *(const float4*)&src[e];
    float4 b = *(const float4*)&src[e + 4];
    float v[8] = {a.x, a.y, a.z, a.w, b.x, b.y, b.z, b.w};
    f16x8 hi, lo;
    #pragma unroll
    for (int j = 0; j < 8; ++j) {
        float s = v[j] * 64.f;                  // pow2 scale: keep lo out of denorms
        _Float16 h = (_Float16)s;
        hi[j] = h; lo[j] = (_Float16)(s - (float)h);
    }
    if (mi == 0)      { *(f16x8*)&hq[e] = hi; *(f16x8*)&lq[e] = lo; }
    else if (mi == 1) { *(f16x8*)&hk[e] = hi; *(f16x8*)&lk[e] = lo; }
    else if (mi == 2) { *(f16x8*)&hv[e] = hi; }
    else              { *(f16x8*)&ho[e] = hi; }
}

// ---------------- mask bit-pack -----------------------------------------------
__global__ __launch_bounds__(256)
void maskpack(const int* __restrict__ mask, unsigned long long* __restrict__ mbits)
{
    int wid  = (blockIdx.x * 256 + threadIdx.x) >> 6;
    int lane = threadIdx.x & 63;
    int v = mask[(size_t)wid * 64 + lane];
    unsigned long long bal = __ballot(v != 0);
    if (lane == 0) mbits[wid] = bal;
}

// ---------------- GEMM body: C = X @ (64*W)^T / 64 + bias (BM=128) ------------
// NPROD: 3 = split f16 (hh+hl+lh), 1 = hi only. A fp32, converted in-kernel.
// OUT_MODE 1: f16 hi/lo scatter [B][H][S][DK]; 2: f16 scatter [B][H][DK][S].
template<int NPROD, int OUT_MODE>
__device__ __forceinline__
void gemm_body(char* smem, const float* __restrict__ Ap,
               const _Float16* __restrict__ Bhi, const _Float16* __restrict__ Blo,
               const float* __restrict__ bias, void* __restrict__ outp, int gid)
{
    _Float16* AhiS = (_Float16*)smem;              // 8KB
    _Float16* BhiS = (_Float16*)(smem + 8192);     // 8KB
    _Float16* AloS = (_Float16*)(smem + 16384);    // 8KB (NPROD3)
    _Float16* BloS = (_Float16*)(smem + 24576);    // 8KB (NPROD3)

    const int tid  = threadIdx.x;
    const int lane = tid & 63, w = tid >> 6;
    const int lx   = lane & 15, lg = lane >> 4;
    const int wm   = w >> 1, wn = w & 1;

    int nid = (gid & 7) * 32 + (gid >> 3);
    const int colBase = (nid & 7) * 128;
    const int rowBase = (nid >> 3) * 128;

    f32x4 acc[4][4];
    #pragma unroll
    for (int i = 0; i < 4; ++i)
        #pragma unroll
        for (int j = 0; j < 4; ++j) acc[i][j] = (f32x4){0.f, 0.f, 0.f, 0.f};

    const int sr = tid >> 1, sh = tid & 1;

    for (int k0 = 0; k0 < D_; k0 += 32) {
        __syncthreads();
        #pragma unroll
        for (int ii = 0; ii < 2; ++ii) {
            int i  = w * 2 + ii;
            int rr = i * 16 + (lane >> 2);
            int cc = (lane & 3) ^ ((lane >> 2) & 3);
            gload16(Bhi + (size_t)(colBase + rr) * D_ + k0 + cc * 8, &BhiS[i * 512]);
            if (NPROD == 3)
                gload16(Blo + (size_t)(colBase + rr) * D_ + k0 + cc * 8, &BloS[i * 512]);
        }
        {
            char* bp = (char*)AhiS + sr * 64;
            int c0 = sh * 2;
            const float* ap = Ap + (size_t)(rowBase + sr) * D_ + k0 + sh * 16;
            float4 x0 = *(const float4*)ap;
            float4 x1 = *(const float4*)(ap + 4);
            float4 x2 = *(const float4*)(ap + 8);
            float4 x3 = *(const float4*)(ap + 12);
            float xv[16] = {x0.x,x0.y,x0.z,x0.w, x1.x,x1.y,x1.z,x1.w,
                            x2.x,x2.y,x2.z,x2.w, x3.x,x3.y,x3.z,x3.w};
            f16x8 hi[2], lo[2];
            #pragma unroll
            for (int j = 0; j < 16; ++j) {
                _Float16 hv = (_Float16)xv[j];
                hi[j >> 3][j & 7] = hv;
                if (NPROD == 3) lo[j >> 3][j & 7] = (_Float16)(xv[j] - (float)hv);
            }
            *(f16x8*)(bp + 16 * ((c0 + 0) ^ (sr & 3))) = hi[0];
            *(f16x8*)(bp + 16 * ((c0 + 1) ^ (sr & 3))) = hi[1];
            if (NPROD == 3) {
                char* lp = (char*)AloS + sr * 64;
                *(f16x8*)(lp + 16 * ((c0 + 0) ^ (sr & 3))) = lo[0];
                *(f16x8*)(lp + 16 * ((c0 + 1) ^ (sr & 3))) = lo[1];
            }
        }
        __syncthreads();

        f16x8 bh[4], bl[4];
        #pragma unroll
        for (int fj = 0; fj < 4; ++fj) {
            int brow = wn * 64 + fj * 16 + lx;
            bh[fj] = *(const f16x8*)((char*)BhiS + brow * 64 + 16 * (lg ^ (brow & 3)));
            if (NPROD == 3)
                bl[fj] = *(const f16x8*)((char*)BloS + brow * 64 + 16 * (lg ^ (brow & 3)));
        }
        #pragma unroll
        for (int fi = 0; fi < 4; ++fi) {
            int arow = wm * 64 + fi * 16 + lx;
            f16x8 ah = *(const f16x8*)((char*)AhiS + arow * 64 + 16 * (lg ^ (arow & 3)));
            f16x8 al;
            if (NPROD == 3)
                al = *(const f16x8*)((char*)AloS + arow * 64 + 16 * (lg ^ (arow & 3)));
            #pragma unroll
            for (int fj = 0; fj < 4; ++fj) {
                acc[fi][fj] = MFMA16(ah, bh[fj], acc[fi][fj]);
                if (NPROD == 3) {
                    acc[fi][fj] = MFMA16(ah, bl[fj], acc[fi][fj]);
                    acc[fi][fj] = MFMA16(al, bh[fj], acc[fi][fj]);
                }
            }
        }
    }

    constexpr float INV = 1.f / 64.f;
    #pragma unroll
    for (int fi = 0; fi < 4; ++fi) {
        #pragma unroll
        for (int fj = 0; fj < 4; ++fj) {
            int n = colBase + wn * 64 + fj * 16 + lx;
            float bv = bias[n];
            if (OUT_MODE == 1) {
                _Float16* Ohi = (_Float16*)outp;
                _Float16* Olo = Ohi + (size_t)M_ * D_;
                int hh = n >> 6, d = n & 63;
                #pragma unroll
                for (int rr = 0; rr < 4; ++rr) {
                    int m = rowBase + wm * 64 + fi * 16 + lg * 4 + rr;
                    int bb = m >> 11, s = m & 2047;
                    float val = acc[fi][fj][rr] * INV + bv;
                    _Float16 hv = (_Float16)val;
                    size_t o = (((size_t)bb * H_ + hh) * S_ + s) * DK_ + d;
                    Ohi[o] = hv;
                    Olo[o] = (_Float16)(val - (float)hv);
                }
            } else {
                _Float16* Vt = (_Float16*)outp;
                int hh = n >> 6, d = n & 63;
                int m0 = rowBase + wm * 64 + fi * 16 + lg * 4;
                int bb = m0 >> 11, s = m0 & 2047;
                f16x4 pk;
                #pragma unroll
                for (int rr = 0; rr < 4; ++rr)
                    pk[rr] = (_Float16)(acc[fi][fj][rr] * INV + bv);
                *(f16x4*)&Vt[(((size_t)bb * H_ + hh) * DK_ + d) * S_ + s] = pk;
            }
        }
    }
}

// ---------------- merged Q/K/V projection: 768 blocks, 3 blocks/CU ------------
__global__ __launch_bounds__(256)
void proj3(const float* __restrict__ query, const float* __restrict__ key_,
           const float* __restrict__ value,
           const _Float16* __restrict__ WhiQ, const _Float16* __restrict__ WloQ,
           const _Float16* __restrict__ WhiK, const _Float16* __restrict__ WloK,
           const _Float16* __restrict__ WhiV,
           const float* __restrict__ bq, const float* __restrict__ bk,
           const float* __restrict__ bv,
           _Float16* __restrict__ Qhi, _Float16* __restrict__ Khi,
           _Float16* __restrict__ VtW)
{
    extern __shared__ char smem[];
    int mode = blockIdx.x >> 8;
    int gid  = blockIdx.x & 255;
    if (mode == 0)
        gemm_body<3, 1>(smem, query, WhiQ, WloQ, bq, Qhi, gid);
    else if (mode == 1)
        gemm_body<3, 1>(smem, key_, WhiK, WloK, bk, Khi, gid);
    else
        gemm_body<1, 2>(smem, value, WhiV, nullptr, bv, VtW, gid);
}

// ---------------- O-proj GEMM: BM=64 x BN=128, A f16, out fp32 ----------------
__global__ __launch_bounds__(256)
void gemm64(const _Float16* __restrict__ Ap, const _Float16* __restrict__ Bhi,
            const float* __restrict__ bias, float* __restrict__ out)
{
    __shared__ __attribute__((aligned(16))) _Float16 AhiS[64 * 32];
    __shared__ __attribute__((aligned(16))) _Float16 BhiS[128 * 32];

    const int tid  = threadIdx.x;
    const int lane = tid & 63, w = tid >> 6;
    const int lx   = lane & 15, lg = lane >> 4;
    const int wm   = w >> 1, wn = w & 1;

    int gid = blockIdx.x;
    int nid = (gid & 7) * 64 + (gid >> 3);
    const int colBase = (nid & 7) * 128;
    const int rowBase = (nid >> 3) * 64;

    f32x4 acc[2][4];
    #pragma unroll
    for (int i = 0; i < 2; ++i)
        #pragma unroll
        for (int j = 0; j < 4; ++j) acc[i][j] = (f32x4){0.f, 0.f, 0.f, 0.f};

    const int sr = tid >> 2, sh = tid & 3;

    for (int k0 = 0; k0 < D_; k0 += 32) {
        __syncthreads();
        #pragma unroll
        for (int ii = 0; ii < 2; ++ii) {
            int i  = w * 2 + ii;
            int rr = i * 16 + (lane >> 2);
            int cc = (lane & 3) ^ ((lane >> 2) & 3);
            gload16(Bhi + (size_t)(colBase + rr) * D_ + k0 + cc * 8, &BhiS[i * 512]);
        }
        {
            const _Float16* ap = Ap + (size_t)(rowBase + sr) * D_ + k0 + sh * 8;
            f16x8 h0 = *(const f16x8*)ap;
            *(f16x8*)((char*)AhiS + sr * 64 + 16 * (sh ^ (sr & 3))) = h0;
        }
        __syncthreads();

        f16x8 bh[4];
        #pragma unroll
        for (int fj = 0; fj < 4; ++fj) {
            int brow = wn * 64 + fj * 16 + lx;
            bh[fj] = *(const f16x8*)((char*)BhiS + brow * 64 + 16 * (lg ^ (brow & 3)));
        }
        #pragma unroll
        for (int fi = 0; fi < 2; ++fi) {
            int arow = wm * 32 + fi * 16 + lx;
            f16x8 ah = *(const f16x8*)((char*)AhiS + arow * 64 + 16 * (lg ^ (arow & 3)));
            #pragma unroll
            for (int fj = 0; fj < 4; ++fj)
                acc[fi][fj] = MFMA16(ah, bh[fj], acc[fi][fj]);
        }
    }

    constexpr float INV = 1.f / 64.f;
    #pragma unroll
    for (int fi = 0; fi < 2; ++fi) {
        #pragma unroll
        for (int fj = 0; fj < 4; ++fj) {
            int n = colBase + wn * 64 + fj * 16 + lx;
            float bv = bias[n];
            #pragma unroll
            for (int rr = 0; rr < 4; ++rr) {
                int m = rowBase + wm * 32 + fi * 16 + lg * 4 + rr;
                out[(size_t)m * D_ + n] = acc[fi][fj][rr] * INV + bv;
            }
        }
    }
}

// ---------------- MFMA flash attention v4: 8 waves, 1 qg/wave -----------------
// scores = mask ? exp(q.k)/8 : -1e9 ; softmax over k ; octx = (P V) merged heads
__global__ __launch_bounds__(512, 4)
void flash_mfma(const _Float16* __restrict__ Qhi, const _Float16* __restrict__ Qlo,
                const _Float16* __restrict__ Khi, const _Float16* __restrict__ Klo,
                const _Float16* __restrict__ Vt, const unsigned long long* __restrict__ Mb,
                _Float16* __restrict__ octx)
{
    __shared__ __attribute__((aligned(16))) _Float16 KhiS[64 * 64];
    __shared__ __attribute__((aligned(16))) _Float16 KloS[64 * 64];
    __shared__ __attribute__((aligned(16))) _Float16 VtS[64 * 64];
    __shared__ __attribute__((aligned(16))) _Float16 PwS[8][16 * 64];  // per-wave P

    const int tid  = threadIdx.x;
    const int lane = tid & 63;
    const int w    = tid >> 6;      // 0..7
    const int lx   = lane & 15;
    const int lg   = lane >> 4;

    // XCD swizzle over 512 blocks (64 per XCD)
    int bid = blockIdx.x;
    int swz = (bid & 7) * 64 + (bid >> 3);
    int qb = swz & 15;
    int h  = (swz >> 4) & 15;
    int b  = swz >> 8;

    const int q0 = qb * 128;
    const size_t bh = (size_t)b * H_ + h;
    const _Float16* KhiG = Khi + bh * S_ * DK_;
    const _Float16* KloG = Klo + bh * S_ * DK_;
    const _Float16* VtG  = Vt  + bh * DK_ * S_;

    // ---- Q fragments (B-operand): qrow = q0 + w*16 + lx, dk = lg*8+j
    const int qrow = q0 + w * 16 + lx;
    f16x8 qh[2], ql[2];
    {
        const _Float16* ph = Qhi + bh * S_ * DK_ + (size_t)qrow * DK_ + lg * 8;
        const _Float16* pl = Qlo + bh * S_ * DK_ + (size_t)qrow * DK_ + lg * 8;
        qh[0] = *(const f16x8*)ph;
        qh[1] = *(const f16x8*)(ph + 32);
        ql[0] = *(const f16x8*)pl;
        ql[1] = *(const f16x8*)(pl + 32);
    }

    f32x4 oacc[4];
    float m_run = -1e30f, l_run = 0.f;
    #pragma unroll
    for (int dt = 0; dt < 4; ++dt) oacc[dt] = (f32x4){0.f, 0.f, 0.f, 0.f};

    char* Pw = (char*)&PwS[w][0];
    const unsigned long long* mrow = Mb + ((size_t)b * S_ + qrow) * (S_ / 64);

    for (int s0 = 0; s0 < S_; s0 += 64) {
        __syncthreads();   // prior tile's LDS reads done

        // stage K hi/lo + V^T: wave w stages its 1KB chunk of each array
        {
            int rr = w * 8 + (lane >> 3);
            int cc = (lane & 7) ^ (lane >> 3);
            gload16(KhiG + (size_t)(s0 + rr) * DK_ + cc * 8, &KhiS[w * 512]);
            gload16(KloG + (size_t)(s0 + rr) * DK_ + cc * 8, &KloS[w * 512]);
            gload16(VtG + (size_t)rr * S_ + s0 + cc * 8, &VtS[w * 512]);
        }
        unsigned long long mw = mrow[s0 >> 6];
        __syncthreads();

        // ---- swapped QK^T: s^T[kcol][qrow]; lane: qrow=lx, kcol=ct*16+lg*4+r
        float sv[4][4];
        #pragma unroll
        for (int ct = 0; ct < 4; ++ct) {
            int row  = ct * 16 + lx;
            int sw   = (row & 7) << 4;
            int base = row * 128 + lg * 16;
            f16x8 kh0 = *(const f16x8*)((const char*)KhiS + ((base +  0) ^ sw));
            f16x8 kh1 = *(const f16x8*)((const char*)KhiS + ((base + 64) ^ sw));
            f16x8 kl0 = *(const f16x8*)((const char*)KloS + ((base +  0) ^ sw));
            f16x8 kl1 = *(const f16x8*)((const char*)KloS + ((base + 64) ^ sw));
            f32x4 s = (f32x4){0.f, 0.f, 0.f, 0.f};
            s = MFMA16(kh0, qh[0], s);
            s = MFMA16(kh1, qh[1], s);
            s = MFMA16(kl0, qh[0], s);
            s = MFMA16(kl1, qh[1], s);
            s = MFMA16(kh0, ql[0], s);
            s = MFMA16(kh1, ql[1], s);
            #pragma unroll
            for (int r = 0; r < 4; ++r) sv[ct][r] = s[r];
        }

        // ---- softmax (lane-local row state; row = qrow, cols = mask bits)
        unsigned long long ms = mw >> (lg * 4);
        float tv[16];
        #pragma unroll
        for (int ct = 0; ct < 4; ++ct)
            #pragma unroll
            for (int r = 0; r < 4; ++r) {
                float e = __expf(sv[ct][r] - 2.0794415416798357f); // exp(s)/8
                tv[ct * 4 + r] = ((ms >> (ct * 16 + r)) & 1ull) ? e : -1e30f;
            }
        float m01 = fmaxf(fmaxf(tv[0], tv[1]), fmaxf(tv[2], tv[3]));
        float m23 = fmaxf(fmaxf(tv[4], tv[5]), fmaxf(tv[6], tv[7]));
        float m45 = fmaxf(fmaxf(tv[8], tv[9]), fmaxf(tv[10], tv[11]));
        float m67 = fmaxf(fmaxf(tv[12], tv[13]), fmaxf(tv[14], tv[15]));
        float tmax = fmaxf(fmaxf(m01, m23), fmaxf(m45, m67));
        tmax = fmaxf(tmax, __shfl_xor(tmax, 16));
        tmax = fmaxf(tmax, __shfl_xor(tmax, 32));

        if (__any(tmax > m_run)) {       // rescale needed (rare after warmup)
            float mn = fmaxf(m_run, tmax);
            float scl = __expf(m_run - mn);
            m_run = mn;
            l_run *= scl;
            #pragma unroll
            for (int dt = 0; dt < 4; ++dt)
                #pragma unroll
                for (int r = 0; r < 4; ++r) oacc[dt][r] *= scl;
        }
        float mr = m_run;
        float pp[16], sum = 0.f;
        #pragma unroll
        for (int i = 0; i < 16; ++i) {
            pp[i] = __expf(tv[i] - mr);
            sum += pp[i];
        }
        sum += __shfl_xor(sum, 16);
        sum += __shfl_xor(sum, 32);
        l_run += sum;

        // pack P pairs (k-adjacent) -> swizzled per-wave buffer
        {
            int psw = (lx & 7) << 4;
            #pragma unroll
            for (int ct = 0; ct < 4; ++ct) {
                fp16x2 a = __builtin_amdgcn_cvt_pkrtz(pp[ct * 4 + 0], pp[ct * 4 + 1]);
                fp16x2 c = __builtin_amdgcn_cvt_pkrtz(pp[ct * 4 + 2], pp[ct * 4 + 3]);
                unsigned int au, cu;
                __builtin_memcpy(&au, &a, 4);
                __builtin_memcpy(&cu, &c, 4);
                int off = lx * 128 + ct * 32 + lg * 8;
                *(unsigned int*)(Pw + ((off + 0) ^ psw)) = au;
                *(unsigned int*)(Pw + ((off + 4) ^ psw)) = cu;
            }
        }

        // ---- PV as O^T = V^T . P^T : A = Vt frags, B = P frags
        f16x8 pa0, pa1;
        {
            int psw = (lx & 7) << 4;
            int pb  = lx * 128 + lg * 16;
            pa0 = *(const f16x8*)(Pw + ((pb +  0) ^ psw));
            pa1 = *(const f16x8*)(Pw + ((pb + 64) ^ psw));
        }
        #pragma unroll
        for (int dt = 0; dt < 4; ++dt) {
            int vrow = dt * 16 + lx;
            int vs   = (vrow & 7) << 4;
            int vb   = vrow * 128 + lg * 16;
            f16x8 v0 = *(const f16x8*)((const char*)VtS + ((vb +  0) ^ vs));
            f16x8 v1 = *(const f16x8*)((const char*)VtS + ((vb + 64) ^ vs));
            oacc[dt] = MFMA16(v0, pa0, oacc[dt]);
            oacc[dt] = MFMA16(v1, pa1, oacc[dt]);
        }
    }

    // ---- epilogue: O^T frag -> octx[b][s][h*64+d], d = dt*16+lg*4+r
    {
        float inv = 1.0f / l_run;
        #pragma unroll
        for (int dt = 0; dt < 4; ++dt) {
            f16x4 o;
            #pragma unroll
            for (int r = 0; r < 4; ++r) o[r] = (_Float16)(oacc[dt][r] * inv);
            *(f16x4*)&octx[((size_t)b * S_ + qrow) * D_ + h * DK_ + dt * 16 + lg * 4] = o;
        }
    }
}

extern "C" void kernel_launch(void* const* d_in, const int* in_sizes, int n_in,
                              void* d_out, int out_size, void* d_ws, size_t ws_size,
                              hipStream_t stream)
{
    const float* query = (const float*)d_in[0];
    const float* key_  = (const float*)d_in[1];
    const float* value = (const float*)d_in[2];
    const int*   mask  = (const int*)d_in[3];
    const float* Wq = (const float*)d_in[4];
    const float* bq = (const float*)d_in[5];
    const float* Wk = (const float*)d_in[6];
    const float* bk = (const float*)d_in[7];
    const float* Wv = (const float*)d_in[8];
    const float* bv = (const float*)d_in[9];
    const float* Wo = (const float*)d_in[10];
    const float* bo = (const float*)d_in[11];

    char* p = (char*)d_ws;
    unsigned long long* mbits = (unsigned long long*)p;  p += (size_t)1 << 20;
    _Float16* WhiQ = (_Float16*)p;  p += (size_t)2 << 20;
    _Float16* WloQ = (_Float16*)p;  p += (size_t)2 << 20;
    _Float16* WhiK = (_Float16*)p;  p += (size_t)2 << 20;
    _Float16* WloK = (_Float16*)p;  p += (size_t)2 << 20;
    _Float16* WhiV = (_Float16*)p;  p += (size_t)2 << 20;
    _Float16* WhiO = (_Float16*)p;  p += (size_t)2 << 20;
    _Float16* Qhi  = (_Float16*)p;  p += (size_t)8 << 20;   // Qlo at +M_*D_
    _Float16* Qlo  = (_Float16*)p;  p += (size_t)8 << 20;
    _Float16* Khi  = (_Float16*)p;  p += (size_t)8 << 20;
    _Float16* Klo  = (_Float16*)p;  p += (size_t)8 << 20;
    _Float16* VtW  = (_Float16*)p;  p += (size_t)8 << 20;
    _Float16* octx = (_Float16*)p;  p += (size_t)8 << 20;
    float* out = (float*)d_out;
    (void)Qlo; (void)Klo;

    maskpack<<<(B_ * S_ * (S_ / 64) * 64) / 256, 256, 0, stream>>>(mask, mbits);
    wsplit<<<2048, 256, 0, stream>>>(Wq, Wk, Wv, Wo,
                                     WhiQ, WloQ, WhiK, WloK, WhiV, WhiO);

    proj3<<<768, 256, 32768, stream>>>(query, key_, value,
                                       WhiQ, WloQ, WhiK, WloK, WhiV,
                                       bq, bk, bv, Qhi, Khi, VtW);

    flash_mfma<<<512, 512, 0, stream>>>(Qhi, Qlo, Khi, Klo, VtW, mbits, octx);

    gemm64<<<512, 256, 0, stream>>>(octx, WhiO, bo, out);
}

// Round 7
// 210.963 us; speedup vs baseline: 5.4154x; 1.0668x over previous
//
#include <hip/hip_runtime.h>
#include <math.h>

#define B_ 2
#define S_ 2048
#define D_ 1024
#define H_ 16
#define DK_ 64
#define M_ (B_*S_)   // 4096

typedef __attribute__((ext_vector_type(8))) _Float16 f16x8;
typedef __attribute__((ext_vector_type(4))) _Float16 f16x4;
typedef __attribute__((ext_vector_type(2))) __fp16 fp16x2;
typedef __attribute__((ext_vector_type(4))) float f32x4;

#define MFMA16(a,b,c) __builtin_amdgcn_mfma_f32_16x16x32_f16((a),(b),(c),0,0,0)

__device__ __forceinline__ void gload16(const void* g, void* l) {
    __builtin_amdgcn_global_load_lds(
        (const __attribute__((address_space(1))) unsigned int*)g,
        (__attribute__((address_space(3))) unsigned int*)l, 16, 0, 0);
}

// ---------------- split pass: all activations & weights -> f16 hi/lo of 64*x --
__global__ __launch_bounds__(256)
void splitall(const float* __restrict__ query, const float* __restrict__ key_,
              const float* __restrict__ value,
              const float* __restrict__ Wq, const float* __restrict__ Wk,
              const float* __restrict__ Wv, const float* __restrict__ Wo,
              _Float16* __restrict__ Xhq, _Float16* __restrict__ Xlq,
              _Float16* __restrict__ Xhk, _Float16* __restrict__ Xlk,
              _Float16* __restrict__ Xhv,
              _Float16* __restrict__ hq, _Float16* __restrict__ lq,
              _Float16* __restrict__ hk, _Float16* __restrict__ lk,
              _Float16* __restrict__ hv, _Float16* __restrict__ ho)
{
    int t = blockIdx.x * 256 + threadIdx.x;   // 2M threads, 8 elems each
    int region = t >> 19;                     // 0=q 1=k 2=v 3=weights
    int u = t & 524287;
    const float* src; _Float16* dhi; _Float16* dlo; size_t e;
    if (region < 3) {
        e = (size_t)u * 8;
        src = (region == 0) ? query : (region == 1) ? key_ : value;
        dhi = (region == 0) ? Xhq : (region == 1) ? Xhk : Xhv;
        dlo = (region == 0) ? Xlq : (region == 1) ? Xlk : nullptr;
    } else {
        int mi = u >> 17;
        e = (size_t)(u & 131071) * 8;
        src = (mi == 0) ? Wq : (mi == 1) ? Wk : (mi == 2) ? Wv : Wo;
        dhi = (mi == 0) ? hq : (mi == 1) ? hk : (mi == 2) ? hv : ho;
        dlo = (mi == 0) ? lq : (mi == 1) ? lk : nullptr;
    }
    float4 a = *(const float4*)&src[e];
    float4 b = *(const float4*)&src[e + 4];
    float v[8] = {a.x, a.y, a.z, a.w, b.x, b.y, b.z, b.w};
    f16x8 hi, lo;
    #pragma unroll
    for (int j = 0; j < 8; ++j) {
        float s = v[j] * 64.f;                // pow2 scale keeps lo out of denorms
        _Float16 h = (_Float16)s;
        hi[j] = h; lo[j] = (_Float16)(s - (float)h);
    }
    *(f16x8*)&dhi[e] = hi;
    if (dlo) *(f16x8*)&dlo[e] = lo;
}

// ---------------- mask bit-pack -----------------------------------------------
__global__ __launch_bounds__(256)
void maskpack(const int* __restrict__ mask, unsigned long long* __restrict__ mbits)
{
    int wid  = (blockIdx.x * 256 + threadIdx.x) >> 6;
    int lane = threadIdx.x & 63;
    int v = mask[(size_t)wid * 64 + lane];
    unsigned long long bal = __ballot(v != 0);
    if (lane == 0) mbits[wid] = bal;
}

// ---------------- GEMM body v2: dbuf prefetch, all-gload16 staging ------------
// C = (64X)(64W)^T/4096 + bias.  NPROD 3: hh+hl+lh split products; 1: hi only.
// OUT_MODE 1: f16 hi/lo scatter [B][H][S][DK] (lo at +M_*D_); 2: [B][H][DK][S].
template<int NPROD, int OUT_MODE>
__device__ __forceinline__
void gemm_body2(char* smem, const _Float16* __restrict__ Ah,
                const _Float16* __restrict__ Al,
                const _Float16* __restrict__ Bh, const _Float16* __restrict__ Bl,
                const float* __restrict__ bias, void* __restrict__ outp, int gid)
{
    constexpr int BUFSZ = (NPROD == 3) ? 32768 : 16384;
    const int tid  = threadIdx.x;
    const int lane = tid & 63, w = tid >> 6;
    const int lx   = lane & 15, lg = lane >> 4;
    const int wm   = w >> 1, wn = w & 1;

    int nid = (gid & 7) * 32 + (gid >> 3);    // XCD-chunked swizzle
    const int colBase = (nid & 7) * 128;
    const int rowBase = (nid >> 3) * 128;

    const int sRow = (lane >> 2);             // staging row within 16-row unit
    const int sChk = (lane & 3) ^ ((lane >> 2) & 3);   // pre-swizzled src chunk

    auto STAGE = [&](int buf, int k0) {
        char* base = smem + buf * BUFSZ;
        #pragma unroll
        for (int ii = 0; ii < 2; ++ii) {
            int i = w * 2 + ii;
            int r = i * 16 + sRow;
            gload16(Ah + (size_t)(rowBase + r) * D_ + k0 + sChk * 8, base + i * 1024);
            gload16(Bh + (size_t)(colBase + r) * D_ + k0 + sChk * 8, base + 8192 + i * 1024);
            if (NPROD == 3) {
                gload16(Al + (size_t)(rowBase + r) * D_ + k0 + sChk * 8, base + 16384 + i * 1024);
                gload16(Bl + (size_t)(colBase + r) * D_ + k0 + sChk * 8, base + 24576 + i * 1024);
            }
        }
    };

    f32x4 acc[4][4];
    #pragma unroll
    for (int i = 0; i < 4; ++i)
        #pragma unroll
        for (int j = 0; j < 4; ++j) acc[i][j] = (f32x4){0.f, 0.f, 0.f, 0.f};

    STAGE(0, 0);
    __syncthreads();                          // drains vmcnt: buf0 ready
    int cur = 0;
    for (int k0 = 0; k0 < D_; k0 += 32) {
        if (k0 + 32 < D_) STAGE(cur ^ 1, k0 + 32);   // prefetch flies under MFMA
        char* base = smem + cur * BUFSZ;
        _Float16* AhS = (_Float16*)base;
        _Float16* BhS = (_Float16*)(base + 8192);
        _Float16* AlS = (_Float16*)(base + 16384);
        _Float16* BlS = (_Float16*)(base + 24576);

        f16x8 bh[4], bl[4];
        #pragma unroll
        for (int fj = 0; fj < 4; ++fj) {
            int brow = wn * 64 + fj * 16 + lx;
            bh[fj] = *(const f16x8*)((char*)BhS + brow * 64 + 16 * (lg ^ (brow & 3)));
            if (NPROD == 3)
                bl[fj] = *(const f16x8*)((char*)BlS + brow * 64 + 16 * (lg ^ (brow & 3)));
        }
        #pragma unroll
        for (int fi = 0; fi < 4; ++fi) {
            int arow = wm * 64 + fi * 16 + lx;
            f16x8 ah = *(const f16x8*)((char*)AhS + arow * 64 + 16 * (lg ^ (arow & 3)));
            f16x8 al;
            if (NPROD == 3)
                al = *(const f16x8*)((char*)AlS + arow * 64 + 16 * (lg ^ (arow & 3)));
            #pragma unroll
            for (int fj = 0; fj < 4; ++fj) {
                acc[fi][fj] = MFMA16(ah, bh[fj], acc[fi][fj]);
                if (NPROD == 3) {
                    acc[fi][fj] = MFMA16(ah, bl[fj], acc[fi][fj]);
                    acc[fi][fj] = MFMA16(al, bh[fj], acc[fi][fj]);
                }
            }
        }
        __syncthreads();                      // reads done + next buf landed
        cur ^= 1;
    }

    constexpr float INV = 1.f / 4096.f;       // (64X)(64W) -> /4096
    #pragma unroll
    for (int fi = 0; fi < 4; ++fi) {
        #pragma unroll
        for (int fj = 0; fj < 4; ++fj) {
            int n = colBase + wn * 64 + fj * 16 + lx;
            float bv = bias[n];
            if (OUT_MODE == 1) {
                _Float16* Ohi = (_Float16*)outp;
                _Float16* Olo = Ohi + (size_t)M_ * D_;
                int hh = n >> 6, d = n & 63;
                #pragma unroll
                for (int rr = 0; rr < 4; ++rr) {
                    int m = rowBase + wm * 64 + fi * 16 + lg * 4 + rr;
                    int bb = m >> 11, s = m & 2047;
                    float val = acc[fi][fj][rr] * INV + bv;
                    _Float16 hv = (_Float16)val;
                    size_t o = (((size_t)bb * H_ + hh) * S_ + s) * DK_ + d;
                    Ohi[o] = hv;
                    Olo[o] = (_Float16)(val - (float)hv);
                }
            } else {
                _Float16* Vt = (_Float16*)outp;
                int hh = n >> 6, d = n & 63;
                int m0 = rowBase + wm * 64 + fi * 16 + lg * 4;
                int bb = m0 >> 11, s = m0 & 2047;
                f16x4 pk;
                #pragma unroll
                for (int rr = 0; rr < 4; ++rr)
                    pk[rr] = (_Float16)(acc[fi][fj][rr] * INV + bv);
                *(f16x4*)&Vt[(((size_t)bb * H_ + hh) * DK_ + d) * S_ + s] = pk;
            }
        }
    }
}

// ---------------- merged Q/K/V projection: 768 blocks --------------------------
__global__ __launch_bounds__(256)
void proj3(const _Float16* __restrict__ Xhq, const _Float16* __restrict__ Xlq,
           const _Float16* __restrict__ Xhk, const _Float16* __restrict__ Xlk,
           const _Float16* __restrict__ Xhv,
           const _Float16* __restrict__ WhiQ, const _Float16* __restrict__ WloQ,
           const _Float16* __restrict__ WhiK, const _Float16* __restrict__ WloK,
           const _Float16* __restrict__ WhiV,
           const float* __restrict__ bq, const float* __restrict__ bk,
           const float* __restrict__ bv,
           _Float16* __restrict__ Qhi, _Float16* __restrict__ Khi,
           _Float16* __restrict__ VtW)
{
    extern __shared__ char smem[];
    int mode = blockIdx.x >> 8;
    int gid  = blockIdx.x & 255;
    if (mode == 0)
        gemm_body2<3, 1>(smem, Xhq, Xlq, WhiQ, WloQ, bq, Qhi, gid);
    else if (mode == 1)
        gemm_body2<3, 1>(smem, Xhk, Xlk, WhiK, WloK, bk, Khi, gid);
    else
        gemm_body2<1, 2>(smem, Xhv, nullptr, WhiV, nullptr, bv, VtW, gid);
}

// ---------------- O-proj GEMM: 64x128 tile, dbuf gload16 both operands --------
__global__ __launch_bounds__(256)
void gemm64(const _Float16* __restrict__ Ap, const _Float16* __restrict__ Bhi,
            const float* __restrict__ bias, float* __restrict__ out)
{
    __shared__ __attribute__((aligned(16))) char smem[24576];  // 2 x (4K A + 8K B)

    const int tid  = threadIdx.x;
    const int lane = tid & 63, w = tid >> 6;
    const int lx   = lane & 15, lg = lane >> 4;
    const int wm   = w >> 1, wn = w & 1;

    int gid = blockIdx.x;
    int nid = (gid & 7) * 64 + (gid >> 3);
    const int colBase = (nid & 7) * 128;
    const int rowBase = (nid >> 3) * 64;

    const int sRow = (lane >> 2);
    const int sChk = (lane & 3) ^ ((lane >> 2) & 3);

    auto STAGE = [&](int buf, int k0) {
        char* base = smem + buf * 12288;
        gload16(Ap + (size_t)(rowBase + w * 16 + sRow) * D_ + k0 + sChk * 8,
                base + w * 1024);
        #pragma unroll
        for (int ii = 0; ii < 2; ++ii) {
            int i = w * 2 + ii;
            int r = i * 16 + sRow;
            gload16(Bhi + (size_t)(colBase + r) * D_ + k0 + sChk * 8,
                    base + 4096 + i * 1024);
        }
    };

    f32x4 acc[2][4];
    #pragma unroll
    for (int i = 0; i < 2; ++i)
        #pragma unroll
        for (int j = 0; j < 4; ++j) acc[i][j] = (f32x4){0.f, 0.f, 0.f, 0.f};

    STAGE(0, 0);
    __syncthreads();
    int cur = 0;
    for (int k0 = 0; k0 < D_; k0 += 32) {
        if (k0 + 32 < D_) STAGE(cur ^ 1, k0 + 32);
        char* base = smem + cur * 12288;
        _Float16* AS = (_Float16*)base;
        _Float16* BS = (_Float16*)(base + 4096);

        f16x8 bh[4];
        #pragma unroll
        for (int fj = 0; fj < 4; ++fj) {
            int brow = wn * 64 + fj * 16 + lx;
            bh[fj] = *(const f16x8*)((char*)BS + brow * 64 + 16 * (lg ^ (brow & 3)));
        }
        #pragma unroll
        for (int fi = 0; fi < 2; ++fi) {
            int arow = wm * 32 + fi * 16 + lx;
            f16x8 ah = *(const f16x8*)((char*)AS + arow * 64 + 16 * (lg ^ (arow & 3)));
            #pragma unroll
            for (int fj = 0; fj < 4; ++fj)
                acc[fi][fj] = MFMA16(ah, bh[fj], acc[fi][fj]);
        }
        __syncthreads();
        cur ^= 1;
    }

    constexpr float INV = 1.f / 64.f;         // A unscaled, B = 64*Wo
    #pragma unroll
    for (int fi = 0; fi < 2; ++fi) {
        #pragma unroll
        for (int fj = 0; fj < 4; ++fj) {
            int n = colBase + wn * 64 + fj * 16 + lx;
            float bv = bias[n];
            #pragma unroll
            for (int rr = 0; rr < 4; ++rr) {
                int m = rowBase + wm * 32 + fi * 16 + lg * 4 + rr;
                out[(size_t)m * D_ + n] = acc[fi][fj][rr] * INV + bv;
            }
        }
    }
}

// ---------------- MFMA flash attention: 8 waves, swapped QK^T (unchanged) -----
__global__ __launch_bounds__(512, 4)
void flash_mfma(const _Float16* __restrict__ Qhi, const _Float16* __restrict__ Qlo,
                const _Float16* __restrict__ Khi, const _Float16* __restrict__ Klo,
                const _Float16* __restrict__ Vt, const unsigned long long* __restrict__ Mb,
                _Float16* __restrict__ octx)
{
    __shared__ __attribute__((aligned(16))) _Float16 KhiS[64 * 64];
    __shared__ __attribute__((aligned(16))) _Float16 KloS[64 * 64];
    __shared__ __attribute__((aligned(16))) _Float16 VtS[64 * 64];
    __shared__ __attribute__((aligned(16))) _Float16 PwS[8][16 * 64];

    const int tid  = threadIdx.x;
    const int lane = tid & 63;
    const int w    = tid >> 6;
    const int lx   = lane & 15;
    const int lg   = lane >> 4;

    int bid = blockIdx.x;
    int swz = (bid & 7) * 64 + (bid >> 3);
    int qb = swz & 15;
    int h  = (swz >> 4) & 15;
    int b  = swz >> 8;

    const int q0 = qb * 128;
    const size_t bh = (size_t)b * H_ + h;
    const _Float16* KhiG = Khi + bh * S_ * DK_;
    const _Float16* KloG = Klo + bh * S_ * DK_;
    const _Float16* VtG  = Vt  + bh * DK_ * S_;

    const int qrow = q0 + w * 16 + lx;
    f16x8 qh[2], ql[2];
    {
        const _Float16* ph = Qhi + bh * S_ * DK_ + (size_t)qrow * DK_ + lg * 8;
        const _Float16* pl = Qlo + bh * S_ * DK_ + (size_t)qrow * DK_ + lg * 8;
        qh[0] = *(const f16x8*)ph;
        qh[1] = *(const f16x8*)(ph + 32);
        ql[0] = *(const f16x8*)pl;
        ql[1] = *(const f16x8*)(pl + 32);
    }

    f32x4 oacc[4];
    float m_run = -1e30f, l_run = 0.f;
    #pragma unroll
    for (int dt = 0; dt < 4; ++dt) oacc[dt] = (f32x4){0.f, 0.f, 0.f, 0.f};

    char* Pw = (char*)&PwS[w][0];
    const unsigned long long* mrow = Mb + ((size_t)b * S_ + qrow) * (S_ / 64);

    for (int s0 = 0; s0 < S_; s0 += 64) {
        __syncthreads();

        {
            int rr = w * 8 + (lane >> 3);
            int cc = (lane & 7) ^ (lane >> 3);
            gload16(KhiG + (size_t)(s0 + rr) * DK_ + cc * 8, &KhiS[w * 512]);
            gload16(KloG + (size_t)(s0 + rr) * DK_ + cc * 8, &KloS[w * 512]);
            gload16(VtG + (size_t)rr * S_ + s0 + cc * 8, &VtS[w * 512]);
        }
        unsigned long long mw = mrow[s0 >> 6];
        __syncthreads();

        float sv[4][4];
        #pragma unroll
        for (int ct = 0; ct < 4; ++ct) {
            int row  = ct * 16 + lx;
            int sw   = (row & 7) << 4;
            int base = row * 128 + lg * 16;
            f16x8 kh0 = *(const f16x8*)((const char*)KhiS + ((base +  0) ^ sw));
            f16x8 kh1 = *(const f16x8*)((const char*)KhiS + ((base + 64) ^ sw));
            f16x8 kl0 = *(const f16x8*)((const char*)KloS + ((base +  0) ^ sw));
            f16x8 kl1 = *(const f16x8*)((const char*)KloS + ((base + 64) ^ sw));
            f32x4 s = (f32x4){0.f, 0.f, 0.f, 0.f};
            s = MFMA16(kh0, qh[0], s);
            s = MFMA16(kh1, qh[1], s);
            s = MFMA16(kl0, qh[0], s);
            s = MFMA16(kl1, qh[1], s);
            s = MFMA16(kh0, ql[0], s);
            s = MFMA16(kh1, ql[1], s);
            #pragma unroll
            for (int r = 0; r < 4; ++r) sv[ct][r] = s[r];
        }

        unsigned long long ms = mw >> (lg * 4);
        float tv[16];
        #pragma unroll
        for (int ct = 0; ct < 4; ++ct)
            #pragma unroll
            for (int r = 0; r < 4; ++r) {
                float e = __expf(sv[ct][r] - 2.0794415416798357f); // exp(s)/8
                tv[ct * 4 + r] = ((ms >> (ct * 16 + r)) & 1ull) ? e : -1e30f;
            }
        float m01 = fmaxf(fmaxf(tv[0], tv[1]), fmaxf(tv[2], tv[3]));
        float m23 = fmaxf(fmaxf(tv[4], tv[5]), fmaxf(tv[6], tv[7]));
        float m45 = fmaxf(fmaxf(tv[8], tv[9]), fmaxf(tv[10], tv[11]));
        float m67 = fmaxf(fmaxf(tv[12], tv[13]), fmaxf(tv[14], tv[15]));
        float tmax = fmaxf(fmaxf(m01, m23), fmaxf(m45, m67));
        tmax = fmaxf(tmax, __shfl_xor(tmax, 16));
        tmax = fmaxf(tmax, __shfl_xor(tmax, 32));

        if (__any(tmax > m_run)) {
            float mn = fmaxf(m_run, tmax);
            float scl = __expf(m_run - mn);
            m_run = mn;
            l_run *= scl;
            #pragma unroll
            for (int dt = 0; dt < 4; ++dt)
                #pragma unroll
                for (int r = 0; r < 4; ++r) oacc[dt][r] *= scl;
        }
        float mr = m_run;
        float pp[16], sum = 0.f;
        #pragma unroll
        for (int i = 0; i < 16; ++i) {
            pp[i] = __expf(tv[i] - mr);
            sum += pp[i];
        }
        sum += __shfl_xor(sum, 16);
        sum += __shfl_xor(sum, 32);
        l_run += sum;

        {
            int psw = (lx & 7) << 4;
            #pragma unroll
            for (int ct = 0; ct < 4; ++ct) {
                fp16x2 a = __builtin_amdgcn_cvt_pkrtz(pp[ct * 4 + 0], pp[ct * 4 + 1]);
                fp16x2 c = __builtin_amdgcn_cvt_pkrtz(pp[ct * 4 + 2], pp[ct * 4 + 3]);
                unsigned int au, cu;
                __builtin_memcpy(&au, &a, 4);
                __builtin_memcpy(&cu, &c, 4);
                int off = lx * 128 + ct * 32 + lg * 8;
                *(unsigned int*)(Pw + ((off + 0) ^ psw)) = au;
                *(unsigned int*)(Pw + ((off + 4) ^ psw)) = cu;
            }
        }

        f16x8 pa0, pa1;
        {
            int psw = (lx & 7) << 4;
            int pb  = lx * 128 + lg * 16;
            pa0 = *(const f16x8*)(Pw + ((pb +  0) ^ psw));
            pa1 = *(const f16x8*)(Pw + ((pb + 64) ^ psw));
        }
        #pragma unroll
        for (int dt = 0; dt < 4; ++dt) {
            int vrow = dt * 16 + lx;
            int vs   = (vrow & 7) << 4;
            int vb   = vrow * 128 + lg * 16;
            f16x8 v0 = *(const f16x8*)((const char*)VtS + ((vb +  0) ^ vs));
            f16x8 v1 = *(const f16x8*)((const char*)VtS + ((vb + 64) ^ vs));
            oacc[dt] = MFMA16(v0, pa0, oacc[dt]);
            oacc[dt] = MFMA16(v1, pa1, oacc[dt]);
        }
    }

    {
        float inv = 1.0f / l_run;
        #pragma unroll
        for (int dt = 0; dt < 4; ++dt) {
            f16x4 o;
            #pragma unroll
            for (int r = 0; r < 4; ++r) o[r] = (_Float16)(oacc[dt][r] * inv);
            *(f16x4*)&octx[((size_t)b * S_ + qrow) * D_ + h * DK_ + dt * 16 + lg * 4] = o;
        }
    }
}

extern "C" void kernel_launch(void* const* d_in, const int* in_sizes, int n_in,
                              void* d_out, int out_size, void* d_ws, size_t ws_size,
                              hipStream_t stream)
{
    const float* query = (const float*)d_in[0];
    const float* key_  = (const float*)d_in[1];
    const float* value = (const float*)d_in[2];
    const int*   mask  = (const int*)d_in[3];
    const float* Wq = (const float*)d_in[4];
    const float* bq = (const float*)d_in[5];
    const float* Wk = (const float*)d_in[6];
    const float* bk = (const float*)d_in[7];
    const float* Wv = (const float*)d_in[8];
    const float* bv = (const float*)d_in[9];
    const float* Wo = (const float*)d_in[10];
    const float* bo = (const float*)d_in[11];

    char* p = (char*)d_ws;
    unsigned long long* mbits = (unsigned long long*)p;  p += (size_t)1 << 20;
    _Float16* WhiQ = (_Float16*)p;  p += (size_t)2 << 20;
    _Float16* WloQ = (_Float16*)p;  p += (size_t)2 << 20;
    _Float16* WhiK = (_Float16*)p;  p += (size_t)2 << 20;
    _Float16* WloK = (_Float16*)p;  p += (size_t)2 << 20;
    _Float16* WhiV = (_Float16*)p;  p += (size_t)2 << 20;
    _Float16* WhiO = (_Float16*)p;  p += (size_t)2 << 20;
    _Float16* Xhq  = (_Float16*)p;  p += (size_t)8 << 20;
    _Float16* Xlq  = (_Float16*)p;  p += (size_t)8 << 20;
    _Float16* Xhk  = (_Float16*)p;  p += (size_t)8 << 20;
    _Float16* Xlk  = (_Float16*)p;  p += (size_t)8 << 20;
    _Float16* Xhv  = (_Float16*)p;  p += (size_t)8 << 20;
    _Float16* Qhi  = (_Float16*)p;  p += (size_t)16 << 20;  // lo at +M_*D_
    _Float16* Khi  = (_Float16*)p;  p += (size_t)16 << 20;  // lo at +M_*D_
    _Float16* VtW  = (_Float16*)p;  p += (size_t)8 << 20;
    _Float16* octx = (_Float16*)p;  p += (size_t)8 << 20;
    float* out = (float*)d_out;

    _Float16* Qlo = Qhi + (size_t)M_ * D_;
    _Float16* Klo = Khi + (size_t)M_ * D_;

    maskpack<<<(B_ * S_ * (S_ / 64) * 64) / 256, 256, 0, stream>>>(mask, mbits);
    splitall<<<8192, 256, 0, stream>>>(query, key_, value, Wq, Wk, Wv, Wo,
                                       Xhq, Xlq, Xhk, Xlk, Xhv,
                                       WhiQ, WloQ, WhiK, WloK, WhiV, WhiO);

    proj3<<<768, 256, 65536, stream>>>(Xhq, Xlq, Xhk, Xlk, Xhv,
                                       WhiQ, WloQ, WhiK, WloK, WhiV,
                                       bq, bk, bv, Qhi, Khi, VtW);

    flash_mfma<<<512, 512, 0, stream>>>(Qhi, Qlo, Khi, Klo, VtW, mbits, octx);

    gemm64<<<512, 256, 0, stream>>>(octx, WhiO, bo, out);
}